// Round 9
// baseline (454.849 us; speedup 1.0000x reference)
//
#include <hip/hip_runtime.h>
#include <math.h>

#define N_NODES 50000
#define N_EDGES 800000
#define ETOT    (N_EDGES + N_NODES)
#define EPAD_MAX 1200000   // >= sum of per-node degrees rounded up to mult of 8
#define IN_CH   128
#define OUT_CH  40
#define NEG     0.2f
#define CAP     128        // max cached slots per node

typedef __attribute__((ext_vector_type(8))) short bf16x8;
typedef __attribute__((ext_vector_type(4))) float f32x4;

__device__ inline unsigned short f2bf(float f) {
    unsigned int u = __float_as_uint(f);
    return (unsigned short)((u + 0x7FFFu + ((u >> 16) & 1u)) >> 16);
}
__device__ inline float bf2f(unsigned short u) {
    return __uint_as_float((unsigned int)u << 16);
}
__device__ inline float bf2f_lo(unsigned int u) {
    return __uint_as_float(u << 16);
}
__device__ inline float bf2f_hi(unsigned int u) {
    return __uint_as_float(u & 0xFFFF0000u);
}
__device__ inline unsigned int pack2bf(float lo, float hi) {
    return (unsigned int)f2bf(lo) | ((unsigned int)f2bf(hi) << 16);
}
__device__ inline float lrelu(float a) { return (a > 0.f) ? a : NEG * a; }

// ---------------------------------------------------------------------------
// CSR build: histogram of dst, exclusive scan over degrees padded to 8, scatter
// ---------------------------------------------------------------------------
__global__ void k_hist(const int* __restrict__ ei, int* __restrict__ deg) {
    int i = blockIdx.x * blockDim.x + threadIdx.x;
    if (i >= ETOT) return;
    int d = (i < N_EDGES) ? ei[N_EDGES + i] : (i - N_EDGES);
    atomicAdd(&deg[d], 1);
}

__global__ void k_scan1(const int* __restrict__ deg, int* __restrict__ start,
                        int* __restrict__ bsum) {
    __shared__ int sh[256];
    int tid = threadIdx.x;
    int i = blockIdx.x * 256 + tid;
    int v = (i < N_NODES) ? ((deg[i] + 7) & ~7) : 0;   // padded degree
    int x = v;
    sh[tid] = x;
    __syncthreads();
    #pragma unroll
    for (int off = 1; off < 256; off <<= 1) {
        int t = (tid >= off) ? sh[tid - off] : 0;
        __syncthreads();
        x += t;
        sh[tid] = x;
        __syncthreads();
    }
    if (i < N_NODES) start[i] = x - v;
    if (tid == 255) bsum[blockIdx.x] = x;
}

__global__ void k_scan2(int* __restrict__ bsum, int nb) {
    __shared__ int sh[256];
    int tid = threadIdx.x;
    int v = (tid < nb) ? bsum[tid] : 0;
    int x = v;
    sh[tid] = x;
    __syncthreads();
    #pragma unroll
    for (int off = 1; off < 256; off <<= 1) {
        int t = (tid >= off) ? sh[tid - off] : 0;
        __syncthreads();
        x += t;
        sh[tid] = x;
        __syncthreads();
    }
    if (tid < nb) bsum[tid] = x - v;
}

__global__ void k_scan3(int* __restrict__ start, const int* __restrict__ bsum) {
    int i = blockIdx.x * 256 + threadIdx.x;
    if (i < N_NODES) start[i] += bsum[blockIdx.x];
}

__global__ void k_scatter(const int* __restrict__ ei, const int* __restrict__ start,
                          int* __restrict__ fill, int* __restrict__ eSrc) {
    int i = blockIdx.x * blockDim.x + threadIdx.x;
    if (i >= ETOT) return;
    int s, d;
    if (i < N_EDGES) { s = ei[i]; d = ei[N_EDGES + i]; }
    else             { s = i - N_EDGES; d = s; }
    int pos = start[d] + atomicAdd(&fill[d], 1);
    eSrc[pos] = s;
}

// ---------------------------------------------------------------------------
// Weight transpose cast: W[K][N] fp32 -> Wt[Npad][K] bf16
// ---------------------------------------------------------------------------
__global__ void k_wt(const float* __restrict__ W, unsigned short* __restrict__ Wt,
                     int K, int Ncol, int Npad) {
    int i = blockIdx.x * blockDim.x + threadIdx.x;
    if (i >= Npad * K) return;
    int n = i / K, k = i - n * K;
    Wt[n * K + k] = (n < Ncol) ? f2bf(W[(long)k * Ncol + n]) : (unsigned short)0;
}

// ---------------------------------------------------------------------------
// bf16 MFMA GEMM. CVT=true: A is fp32, converted to bf16 during LDS staging.
// ---------------------------------------------------------------------------
#define PITCH 40
template<int BN, int FM, int FN, bool CVT>
__global__ __launch_bounds__(256) void k_mfma(const void* __restrict__ Araw,
                                              const unsigned short* __restrict__ Bt,
                                              unsigned short* __restrict__ C,
                                              int M, int K, int Ncol) {
    __shared__ unsigned short As[128 * PITCH];
    __shared__ unsigned short Bs[BN * PITCH];
    const int WCOLS = BN / (FN * 16);
    int tid = threadIdx.x;
    int wave = tid >> 6, lane = tid & 63;
    int quad = lane >> 4, l16 = lane & 15;
    int wr = wave / WCOLS, wc = wave % WCOLS;
    long row0 = (long)blockIdx.x * 128;
    int col0 = blockIdx.y * BN;

    f32x4 acc[FM][FN] = {};

    for (int k0 = 0; k0 < K; k0 += 32) {
        for (int c = tid; c < 512; c += 256) {
            int r = c >> 2, kp = (c & 3) << 3;
            long gr = row0 + r;
            if (CVT) {
                const float* A32 = (const float*)Araw;
                ushort4 lo = {0,0,0,0}, hi = {0,0,0,0};
                if (gr < M) {
                    float4 v0 = *(const float4*)(A32 + gr * K + k0 + kp);
                    float4 v1 = *(const float4*)(A32 + gr * K + k0 + kp + 4);
                    lo.x = f2bf(v0.x); lo.y = f2bf(v0.y); lo.z = f2bf(v0.z); lo.w = f2bf(v0.w);
                    hi.x = f2bf(v1.x); hi.y = f2bf(v1.y); hi.z = f2bf(v1.z); hi.w = f2bf(v1.w);
                }
                *(ushort4*)(As + r * PITCH + kp) = lo;
                *(ushort4*)(As + r * PITCH + kp + 4) = hi;
            } else {
                const unsigned short* A16 = (const unsigned short*)Araw;
                uint4 v = {0u, 0u, 0u, 0u};
                if (gr < M) v = *(const uint4*)(A16 + gr * K + k0 + kp);
                *(uint4*)(As + r * PITCH + kp) = v;
            }
        }
        for (int c = tid; c < BN * 4; c += 256) {
            int r = c >> 2, kp = (c & 3) << 3;
            uint4 v = *(const uint4*)(Bt + (long)(col0 + r) * K + k0 + kp);
            *(uint4*)(Bs + r * PITCH + kp) = v;
        }
        __syncthreads();
        bf16x8 af[FM], bfr[FN];
        #pragma unroll
        for (int i = 0; i < FM; ++i)
            af[i] = *(const bf16x8*)(As + (wr * FM * 16 + i * 16 + l16) * PITCH + quad * 8);
        #pragma unroll
        for (int j = 0; j < FN; ++j)
            bfr[j] = *(const bf16x8*)(Bs + (wc * FN * 16 + j * 16 + l16) * PITCH + quad * 8);
        #pragma unroll
        for (int i = 0; i < FM; ++i)
            #pragma unroll
            for (int j = 0; j < FN; ++j)
                acc[i][j] = __builtin_amdgcn_mfma_f32_16x16x32_bf16(af[i], bfr[j], acc[i][j], 0, 0, 0);
        __syncthreads();
    }

    #pragma unroll
    for (int i = 0; i < FM; ++i) {
        long rowb = row0 + wr * FM * 16 + i * 16 + quad * 4;
        #pragma unroll
        for (int j = 0; j < FN; ++j) {
            int col = col0 + wc * FN * 16 + j * 16 + l16;
            if (col < Ncol) {
                #pragma unroll
                for (int v = 0; v < 4; ++v) {
                    long r = rowb + v;
                    if (r < M) C[r * Ncol + col] = f2bf(acc[i][j][v]);
                }
            }
        }
    }
}

// ---------------------------------------------------------------------------
// Attention logits
// ---------------------------------------------------------------------------
__global__ __launch_bounds__(256) void k_logits4(const unsigned short* __restrict__ h,
                                                 const float* __restrict__ a_s,
                                                 const float* __restrict__ a_d,
                                                 float* __restrict__ als,
                                                 float* __restrict__ ald) {
    int wave = (blockIdx.x * blockDim.x + threadIdx.x) >> 6;
    int lane = threadIdx.x & 63;
    if (wave >= N_NODES) return;
    ushort4 hu = *(const ushort4*)(h + (long)wave * 256 + lane * 4);
    float hx = bf2f(hu.x), hy = bf2f(hu.y), hz = bf2f(hu.z), hw = bf2f(hu.w);
    int head = lane >> 4;
    int cbase = (lane * 4) & 63;
    float4 sv = *(const float4*)(a_s + head * 64 + cbase);
    float4 dv = *(const float4*)(a_d + head * 64 + cbase);
    float ps = hx * sv.x + hy * sv.y + hz * sv.z + hw * sv.w;
    float pd = hx * dv.x + hy * dv.y + hz * dv.z + hw * dv.w;
    #pragma unroll
    for (int off = 1; off < 16; off <<= 1) {
        ps += __shfl_xor(ps, off);
        pd += __shfl_xor(pd, off);
    }
    if ((lane & 15) == 0) {
        als[wave * 4 + head] = ps;
        ald[wave * 4 + head] = pd;
    }
}

__global__ __launch_bounds__(256) void k_logits1(const unsigned short* __restrict__ h,
                                                 const float* __restrict__ a_s,
                                                 const float* __restrict__ a_d,
                                                 float* __restrict__ als,
                                                 float* __restrict__ ald) {
    int wave = (blockIdx.x * blockDim.x + threadIdx.x) >> 6;
    int lane = threadIdx.x & 63;
    if (wave >= N_NODES) return;
    float hv = (lane < OUT_CH) ? bf2f(h[(long)wave * OUT_CH + lane]) : 0.f;
    float ps = (lane < OUT_CH) ? hv * a_s[lane] : 0.f;
    float pd = (lane < OUT_CH) ? hv * a_d[lane] : 0.f;
    #pragma unroll
    for (int off = 1; off < 64; off <<= 1) {
        ps += __shfl_xor(ps, off);
        pd += __shfl_xor(pd, off);
    }
    if (lane == 0) {
        als[wave] = ps;
        ald[wave] = pd;
    }
}

// ---------------------------------------------------------------------------
// Aggregation (4-head), half-wave edge split. Phase 1: cooperative weights
// into LDS (one exp issue covers 16 slots x 4 heads). Phase 2: each half-wave
// (32 lanes) owns one edge, 8 ch/lane via dwordx4 -> one load serves 2 edges.
// Two-ended pair walk (4+4 pairs = 16 edges, 8 loads in flight). Epilogue
// combines halves with shfl_xor(32); half 0 packs bf16 and stores 16 B/lane.
// ---------------------------------------------------------------------------
__global__ __launch_bounds__(256) void k_agg4(const unsigned short* __restrict__ h,
                                              const int* __restrict__ start,
                                              const int* __restrict__ deg,
                                              const int* __restrict__ eSrc,
                                              const float* __restrict__ als,
                                              const float* __restrict__ ald,
                                              const float* __restrict__ bias,
                                              unsigned short* __restrict__ out) {
    __shared__ float wbuf[4][CAP * 4];
    __shared__ int   sbuf[4][CAP];
    int wid = threadIdx.x >> 6;
    int node = (blockIdx.x * blockDim.x + threadIdx.x) >> 6;
    int lane = threadIdx.x & 63;
    if (node >= N_NODES) return;
    int st = start[node];
    int dgp = (deg[node] + 7) & ~7;
    const int* ep = eSrc + st;

    // ---- phase 1: weights into LDS (16 slots x 4 heads per pass) ----
    int l16 = lane & 15, headw = lane >> 4;
    float aldd4 = ald[node * 4 + headw];
    int ncap = (dgp < CAP) ? dgp : CAP;
    for (int c = 0; c < ncap; c += 16) {
        int slot = c + l16;
        bool ok = (slot < ncap);
        int raw = ok ? ep[slot] : -1;
        int ss = (raw < 0) ? 0 : raw;
        float a = als[(long)ss * 4 + headw] + aldd4;
        float w = (raw < 0) ? 0.f : __expf(lrelu(a));
        if (ok) {
            wbuf[wid][slot * 4 + headw] = w;
            if (headw == 0) sbuf[wid][slot] = ss;
        }
    }

    // ---- phase 2: half-wave per edge, 8 ch/lane ----
    int half = lane >> 5;        // which edge of the pair
    int hl = lane & 31;          // half-lane: channels hl*8 .. hl*8+7
    int head8 = hl >> 3;         // head of this lane's channels
    float den = 0.f;
    float acc[8] = {};

    int ncpair = ncap >> 1;      // multiple of 4 (ncap mult of 8)
    int jA = 0, jB = ncpair - 4;

    auto do_pairs = [&](int p0, int p1, int p2, int p3) {
        int slot[4] = {p0 * 2 + half, p1 * 2 + half, p2 * 2 + half, p3 * 2 + half};
        int s[4];
        float w[4];
        #pragma unroll
        for (int u = 0; u < 4; ++u) {
            s[u] = sbuf[wid][slot[u]];
            w[u] = wbuf[wid][slot[u] * 4 + head8];
        }
        uint4 hv[4];
        #pragma unroll
        for (int u = 0; u < 4; ++u)
            hv[u] = *(const uint4*)(h + (long)s[u] * 256 + hl * 8);
        #pragma unroll
        for (int u = 0; u < 4; ++u) {
            den += w[u];
            acc[0] += w[u] * bf2f_lo(hv[u].x);
            acc[1] += w[u] * bf2f_hi(hv[u].x);
            acc[2] += w[u] * bf2f_lo(hv[u].y);
            acc[3] += w[u] * bf2f_hi(hv[u].y);
            acc[4] += w[u] * bf2f_lo(hv[u].z);
            acc[5] += w[u] * bf2f_hi(hv[u].z);
            acc[6] += w[u] * bf2f_lo(hv[u].w);
            acc[7] += w[u] * bf2f_hi(hv[u].w);
        }
    };

    while (jA < jB) {
        do_pairs(jA, jA + 1, jB, jB + 1);
        do_pairs(jA + 2, jA + 3, jB + 2, jB + 3);
        jA += 4; jB -= 4;
    }
    if (jA == jB) {
        do_pairs(jA, jA + 1, jA + 2, jA + 3);
    }

    // ---- overflow beyond CAP (practically never taken) ----
    if (dgp > ncap) {
        float aldd8 = ald[node * 4 + head8];
        for (int j = ncap; j < dgp; j += 2) {
            int raw = ep[j + half];
            int ss = (raw < 0) ? 0 : raw;
            float w = (raw < 0) ? 0.f : __expf(lrelu(als[(long)ss * 4 + head8] + aldd8));
            uint4 hv = *(const uint4*)(h + (long)ss * 256 + hl * 8);
            den += w;
            acc[0] += w * bf2f_lo(hv.x);
            acc[1] += w * bf2f_hi(hv.x);
            acc[2] += w * bf2f_lo(hv.y);
            acc[3] += w * bf2f_hi(hv.y);
            acc[4] += w * bf2f_lo(hv.z);
            acc[5] += w * bf2f_hi(hv.z);
            acc[6] += w * bf2f_lo(hv.w);
            acc[7] += w * bf2f_hi(hv.w);
        }
    }

    // ---- combine the two halves ----
    den += __shfl_xor(den, 32);
    #pragma unroll
    for (int c = 0; c < 8; ++c) acc[c] += __shfl_xor(acc[c], 32);

    if (half == 0) {
        float inv = 1.f / den;
        int cb = hl * 8;
        float4 b0 = *(const float4*)(bias + cb);
        float4 b1 = *(const float4*)(bias + cb + 4);
        float v0 = fmaxf(acc[0] * inv + b0.x, 0.f);
        float v1 = fmaxf(acc[1] * inv + b0.y, 0.f);
        float v2 = fmaxf(acc[2] * inv + b0.z, 0.f);
        float v3 = fmaxf(acc[3] * inv + b0.w, 0.f);
        float v4 = fmaxf(acc[4] * inv + b1.x, 0.f);
        float v5 = fmaxf(acc[5] * inv + b1.y, 0.f);
        float v6 = fmaxf(acc[6] * inv + b1.z, 0.f);
        float v7 = fmaxf(acc[7] * inv + b1.w, 0.f);
        uint4 o;
        o.x = pack2bf(v0, v1);
        o.y = pack2bf(v2, v3);
        o.z = pack2bf(v4, v5);
        o.w = pack2bf(v6, v7);
        *(uint4*)(out + (long)node * 256 + cb) = o;
    }
}

// ---------------------------------------------------------------------------
// Final layer agg: quad-per-edge, two-ended walk, fused weights + bias +
// log_softmax (unchanged from R8).
// ---------------------------------------------------------------------------
__global__ __launch_bounds__(256) void k_agg1(const unsigned short* __restrict__ h,
                                              const int* __restrict__ start,
                                              const int* __restrict__ deg,
                                              const int* __restrict__ eSrc,
                                              const float* __restrict__ als,
                                              const float* __restrict__ ald,
                                              const float* __restrict__ bias,
                                              float* __restrict__ out) {
    int node = (blockIdx.x * blockDim.x + threadIdx.x) >> 6;
    int lane = threadIdx.x & 63;
    if (node >= N_NODES) return;
    int q = lane >> 4, r = lane & 15;
    bool act = (r < 10);
    int st = start[node];
    int dgp = (deg[node] + 7) & ~7;
    const int* ep = eSrc + st;
    float aldd = ald[node];

    float den = 0.f;
    float4 acc = {0.f, 0.f, 0.f, 0.f};

    int jA = 0, jB = dgp - 4;
    while (jA < jB) {
        int r0 = ep[jA + q], r1 = ep[jB + q];
        int s0 = (r0 < 0) ? 0 : r0;
        int s1 = (r1 < 0) ? 0 : r1;
        float w0 = (r0 < 0) ? 0.f : __expf(lrelu(als[s0] + aldd));
        float w1 = (r1 < 0) ? 0.f : __expf(lrelu(als[s1] + aldd));
        ushort4 h0 = {0, 0, 0, 0}, h1 = {0, 0, 0, 0};
        if (act) {
            h0 = *(const ushort4*)(h + (long)s0 * OUT_CH + r * 4);
            h1 = *(const ushort4*)(h + (long)s1 * OUT_CH + r * 4);
        }
        den += w0 + w1;
        acc.x += w0 * bf2f(h0.x) + w1 * bf2f(h1.x);
        acc.y += w0 * bf2f(h0.y) + w1 * bf2f(h1.y);
        acc.z += w0 * bf2f(h0.z) + w1 * bf2f(h1.z);
        acc.w += w0 * bf2f(h0.w) + w1 * bf2f(h1.w);
        jA += 4; jB -= 4;
    }
    if (jA == jB) {
        int r0 = ep[jA + q];
        int s0 = (r0 < 0) ? 0 : r0;
        float w0 = (r0 < 0) ? 0.f : __expf(lrelu(als[s0] + aldd));
        ushort4 h0 = {0, 0, 0, 0};
        if (act) h0 = *(const ushort4*)(h + (long)s0 * OUT_CH + r * 4);
        den += w0;
        acc.x += w0 * bf2f(h0.x);
        acc.y += w0 * bf2f(h0.y);
        acc.z += w0 * bf2f(h0.z);
        acc.w += w0 * bf2f(h0.w);
    }

    #pragma unroll
    for (int off = 16; off < 64; off <<= 1) {
        acc.x += __shfl_xor(acc.x, off);
        acc.y += __shfl_xor(acc.y, off);
        acc.z += __shfl_xor(acc.z, off);
        acc.w += __shfl_xor(acc.w, off);
        den   += __shfl_xor(den, off);
    }
    float inv = 1.f / den;
    float4 bv = {0.f, 0.f, 0.f, 0.f};
    if (act) bv = *(const float4*)(bias + r * 4);
    float4 v;
    v.x = acc.x * inv + bv.x;
    v.y = acc.y * inv + bv.y;
    v.z = acc.z * inv + bv.z;
    v.w = acc.w * inv + bv.w;
    float mx = act ? fmaxf(fmaxf(v.x, v.y), fmaxf(v.z, v.w)) : -INFINITY;
    #pragma unroll
    for (int off = 1; off < 16; off <<= 1) mx = fmaxf(mx, __shfl_xor(mx, off));
    float sum = act ? (__expf(v.x - mx) + __expf(v.y - mx) + __expf(v.z - mx) + __expf(v.w - mx)) : 0.f;
    #pragma unroll
    for (int off = 1; off < 16; off <<= 1) sum += __shfl_xor(sum, off);
    float lse = mx + logf(sum);
    if (q == 0 && act) {
        float4 o;
        o.x = v.x - lse;
        o.y = v.y - lse;
        o.z = v.z - lse;
        o.w = v.w - lse;
        *(float4*)(out + (long)node * OUT_CH + r * 4) = o;
    }
}

// ---------------------------------------------------------------------------
extern "C" void kernel_launch(void* const* d_in, const int* in_sizes, int n_in,
                              void* d_out, int out_size, void* d_ws, size_t ws_size,
                              hipStream_t stream) {
    (void)in_sizes; (void)n_in; (void)out_size; (void)ws_size;
    const float* x   = (const float*)d_in[0];
    const int*   ei  = (const int*)d_in[1];
    const float* W1  = (const float*)d_in[2];
    const float* as1 = (const float*)d_in[3];
    const float* ad1 = (const float*)d_in[4];
    const float* b1  = (const float*)d_in[5];
    const float* W2  = (const float*)d_in[6];
    const float* as2 = (const float*)d_in[7];
    const float* ad2 = (const float*)d_in[8];
    const float* b2  = (const float*)d_in[9];
    const float* W3  = (const float*)d_in[10];
    const float* as3 = (const float*)d_in[11];
    const float* ad3 = (const float*)d_in[12];
    const float* b3  = (const float*)d_in[13];
    float* out = (float*)d_out;

    char* p = (char*)d_ws;
    auto alloc = [&](size_t b) { char* r = p; p += (b + 255) & ~(size_t)255; return r; };
    int*   deg   = (int*)alloc((size_t)N_NODES * 4);
    int*   start = (int*)alloc((size_t)N_NODES * 4);
    int*   fill  = (int*)alloc((size_t)N_NODES * 4);
    int*   bsum  = (int*)alloc(256 * 4);
    int*   eSrc  = (int*)alloc((size_t)EPAD_MAX * 4);
    float* als   = (float*)alloc((size_t)N_NODES * 4 * 4);
    float* ald   = (float*)alloc((size_t)N_NODES * 4 * 4);
    unsigned short* hAbf = (unsigned short*)alloc((size_t)N_NODES * 256 * 2);
    unsigned short* hBbf = (unsigned short*)alloc((size_t)N_NODES * 256 * 2);
    unsigned short* h3bf = (unsigned short*)alloc((size_t)N_NODES * OUT_CH * 2);
    unsigned short* Wt1  = (unsigned short*)alloc((size_t)256 * IN_CH * 2);
    unsigned short* Wt2  = (unsigned short*)alloc((size_t)256 * 256 * 2);
    unsigned short* Wt3  = (unsigned short*)alloc((size_t)64 * 256 * 2);

    const int NB = (N_NODES + 255) / 256;
    const int EB = (ETOT + 255) / 256;
    const int WB = (N_NODES + 3) / 4;
    const int MB = (N_NODES + 127) / 128;

    // ---- CSR build (padded to multiple of 8 per node) ----
    hipMemsetAsync(deg,  0, (size_t)N_NODES * 4, stream);
    hipMemsetAsync(fill, 0, (size_t)N_NODES * 4, stream);
    hipMemsetAsync(eSrc, 0xFF, (size_t)EPAD_MAX * 4, stream);   // pads -> -1
    k_hist<<<EB, 256, 0, stream>>>(ei, deg);
    k_scan1<<<NB, 256, 0, stream>>>(deg, start, bsum);
    k_scan2<<<1, 256, 0, stream>>>(bsum, NB);
    k_scan3<<<NB, 256, 0, stream>>>(start, bsum);
    k_scatter<<<EB, 256, 0, stream>>>(ei, start, fill, eSrc);

    // ---- weight transposes ----
    k_wt<<<(256 * IN_CH + 255) / 256, 256, 0, stream>>>(W1, Wt1, IN_CH, 256, 256);
    k_wt<<<(256 * 256 + 255) / 256, 256, 0, stream>>>(W2, Wt2, 256, 256, 256);
    k_wt<<<(64 * 256 + 255) / 256, 256, 0, stream>>>(W3, Wt3, 256, OUT_CH, 64);

    // ---- layer 1 (fp32 x staged+converted in-GEMM) ----
    k_mfma<128, 4, 4, true><<<dim3(MB, 2), 256, 0, stream>>>(x, Wt1, hAbf, N_NODES, IN_CH, 256);
    k_logits4<<<WB, 256, 0, stream>>>(hAbf, as1, ad1, als, ald);
    k_agg4<<<WB, 256, 0, stream>>>(hAbf, start, deg, eSrc, als, ald, b1, hBbf);

    // ---- layer 2 ----
    k_mfma<128, 4, 4, false><<<dim3(MB, 2), 256, 0, stream>>>(hBbf, Wt2, hAbf, N_NODES, 256, 256);
    k_logits4<<<WB, 256, 0, stream>>>(hAbf, as2, ad2, als, ald);
    k_agg4<<<WB, 256, 0, stream>>>(hAbf, start, deg, eSrc, als, ald, b2, hBbf);

    // ---- layer 3 ----
    k_mfma<64, 2, 4, false><<<dim3(MB, 1), 256, 0, stream>>>(hBbf, Wt3, h3bf, N_NODES, 256, OUT_CH);
    k_logits1<<<WB, 256, 0, stream>>>(h3bf, as3, ad3, als, ald);
    k_agg1<<<WB, 256, 0, stream>>>(h3bf, start, deg, eSrc, als, ald, b3, out);
}

// Round 10
// 410.943 us; speedup vs baseline: 1.1068x; 1.1068x over previous
//
#include <hip/hip_runtime.h>
#include <math.h>

#define N_NODES 50000
#define N_EDGES 800000
#define ETOT    (N_EDGES + N_NODES)
#define EPAD_MAX 1200000   // >= sum of per-node degrees rounded up to mult of 8
#define IN_CH   128
#define OUT_CH  40
#define NEG     0.2f
#define CAP     128        // max cached slots per node

typedef __attribute__((ext_vector_type(8))) short bf16x8;
typedef __attribute__((ext_vector_type(4))) float f32x4;
typedef __attribute__((ext_vector_type(2))) float f32x2;

__device__ inline unsigned short f2bf(float f) {
    unsigned int u = __float_as_uint(f);
    return (unsigned short)((u + 0x7FFFu + ((u >> 16) & 1u)) >> 16);
}
__device__ inline float bf2f(unsigned short u) {
    return __uint_as_float((unsigned int)u << 16);
}
__device__ inline float lrelu(float a) { return (a > 0.f) ? a : NEG * a; }

// fp8 e4m3 pack/unpack via gfx950 native converts
__device__ inline unsigned int pack4fp8(float a, float b, float c, float d) {
    int p = __builtin_amdgcn_cvt_pk_fp8_f32(a, b, 0, false);
    p = __builtin_amdgcn_cvt_pk_fp8_f32(c, d, p, true);
    return (unsigned int)p;
}

// ---------------------------------------------------------------------------
// CSR build: histogram of dst, exclusive scan over degrees padded to 8, scatter
// ---------------------------------------------------------------------------
__global__ void k_hist(const int* __restrict__ ei, int* __restrict__ deg) {
    int i = blockIdx.x * blockDim.x + threadIdx.x;
    if (i >= ETOT) return;
    int d = (i < N_EDGES) ? ei[N_EDGES + i] : (i - N_EDGES);
    atomicAdd(&deg[d], 1);
}

__global__ void k_scan1(const int* __restrict__ deg, int* __restrict__ start,
                        int* __restrict__ bsum) {
    __shared__ int sh[256];
    int tid = threadIdx.x;
    int i = blockIdx.x * 256 + tid;
    int v = (i < N_NODES) ? ((deg[i] + 7) & ~7) : 0;   // padded degree
    int x = v;
    sh[tid] = x;
    __syncthreads();
    #pragma unroll
    for (int off = 1; off < 256; off <<= 1) {
        int t = (tid >= off) ? sh[tid - off] : 0;
        __syncthreads();
        x += t;
        sh[tid] = x;
        __syncthreads();
    }
    if (i < N_NODES) start[i] = x - v;
    if (tid == 255) bsum[blockIdx.x] = x;
}

__global__ void k_scan2(int* __restrict__ bsum, int nb) {
    __shared__ int sh[256];
    int tid = threadIdx.x;
    int v = (tid < nb) ? bsum[tid] : 0;
    int x = v;
    sh[tid] = x;
    __syncthreads();
    #pragma unroll
    for (int off = 1; off < 256; off <<= 1) {
        int t = (tid >= off) ? sh[tid - off] : 0;
        __syncthreads();
        x += t;
        sh[tid] = x;
        __syncthreads();
    }
    if (tid < nb) bsum[tid] = x - v;
}

__global__ void k_scan3(int* __restrict__ start, const int* __restrict__ bsum) {
    int i = blockIdx.x * 256 + threadIdx.x;
    if (i < N_NODES) start[i] += bsum[blockIdx.x];
}

__global__ void k_scatter(const int* __restrict__ ei, const int* __restrict__ start,
                          int* __restrict__ fill, int* __restrict__ eSrc) {
    int i = blockIdx.x * blockDim.x + threadIdx.x;
    if (i >= ETOT) return;
    int s, d;
    if (i < N_EDGES) { s = ei[i]; d = ei[N_EDGES + i]; }
    else             { s = i - N_EDGES; d = s; }
    int pos = start[d] + atomicAdd(&fill[d], 1);
    eSrc[pos] = s;
}

// ---------------------------------------------------------------------------
// Weight transpose cast: W[K][N] fp32 -> Wt[Npad][K] bf16
// ---------------------------------------------------------------------------
__global__ void k_wt(const float* __restrict__ W, unsigned short* __restrict__ Wt,
                     int K, int Ncol, int Npad) {
    int i = blockIdx.x * blockDim.x + threadIdx.x;
    if (i >= Npad * K) return;
    int n = i / K, k = i - n * K;
    Wt[n * K + k] = (n < Ncol) ? f2bf(W[(long)k * Ncol + n]) : (unsigned short)0;
}

// ---------------------------------------------------------------------------
// bf16 MFMA GEMM. CVT=true: A is fp32, converted to bf16 during LDS staging.
// ---------------------------------------------------------------------------
#define PITCH 40
template<int BN, int FM, int FN, bool CVT>
__global__ __launch_bounds__(256) void k_mfma(const void* __restrict__ Araw,
                                              const unsigned short* __restrict__ Bt,
                                              unsigned short* __restrict__ C,
                                              int M, int K, int Ncol) {
    __shared__ unsigned short As[128 * PITCH];
    __shared__ unsigned short Bs[BN * PITCH];
    const int WCOLS = BN / (FN * 16);
    int tid = threadIdx.x;
    int wave = tid >> 6, lane = tid & 63;
    int quad = lane >> 4, l16 = lane & 15;
    int wr = wave / WCOLS, wc = wave % WCOLS;
    long row0 = (long)blockIdx.x * 128;
    int col0 = blockIdx.y * BN;

    f32x4 acc[FM][FN] = {};

    for (int k0 = 0; k0 < K; k0 += 32) {
        for (int c = tid; c < 512; c += 256) {
            int r = c >> 2, kp = (c & 3) << 3;
            long gr = row0 + r;
            if (CVT) {
                const float* A32 = (const float*)Araw;
                ushort4 lo = {0,0,0,0}, hi = {0,0,0,0};
                if (gr < M) {
                    float4 v0 = *(const float4*)(A32 + gr * K + k0 + kp);
                    float4 v1 = *(const float4*)(A32 + gr * K + k0 + kp + 4);
                    lo.x = f2bf(v0.x); lo.y = f2bf(v0.y); lo.z = f2bf(v0.z); lo.w = f2bf(v0.w);
                    hi.x = f2bf(v1.x); hi.y = f2bf(v1.y); hi.z = f2bf(v1.z); hi.w = f2bf(v1.w);
                }
                *(ushort4*)(As + r * PITCH + kp) = lo;
                *(ushort4*)(As + r * PITCH + kp + 4) = hi;
            } else {
                const unsigned short* A16 = (const unsigned short*)Araw;
                uint4 v = {0u, 0u, 0u, 0u};
                if (gr < M) v = *(const uint4*)(A16 + gr * K + k0 + kp);
                *(uint4*)(As + r * PITCH + kp) = v;
            }
        }
        for (int c = tid; c < BN * 4; c += 256) {
            int r = c >> 2, kp = (c & 3) << 3;
            uint4 v = *(const uint4*)(Bt + (long)(col0 + r) * K + k0 + kp);
            *(uint4*)(Bs + r * PITCH + kp) = v;
        }
        __syncthreads();
        bf16x8 af[FM], bfr[FN];
        #pragma unroll
        for (int i = 0; i < FM; ++i)
            af[i] = *(const bf16x8*)(As + (wr * FM * 16 + i * 16 + l16) * PITCH + quad * 8);
        #pragma unroll
        for (int j = 0; j < FN; ++j)
            bfr[j] = *(const bf16x8*)(Bs + (wc * FN * 16 + j * 16 + l16) * PITCH + quad * 8);
        #pragma unroll
        for (int i = 0; i < FM; ++i)
            #pragma unroll
            for (int j = 0; j < FN; ++j)
                acc[i][j] = __builtin_amdgcn_mfma_f32_16x16x32_bf16(af[i], bfr[j], acc[i][j], 0, 0, 0);
        __syncthreads();
    }

    #pragma unroll
    for (int i = 0; i < FM; ++i) {
        long rowb = row0 + wr * FM * 16 + i * 16 + quad * 4;
        #pragma unroll
        for (int j = 0; j < FN; ++j) {
            int col = col0 + wc * FN * 16 + j * 16 + l16;
            if (col < Ncol) {
                #pragma unroll
                for (int v = 0; v < 4; ++v) {
                    long r = rowb + v;
                    if (r < M) C[r * Ncol + col] = f2bf(acc[i][j][v]);
                }
            }
        }
    }
}

// ---------------------------------------------------------------------------
// Attention logits (4-head) + fp8 re-emit of h for the gather kernel.
// ---------------------------------------------------------------------------
__global__ __launch_bounds__(256) void k_logits4(const unsigned short* __restrict__ h,
                                                 const float* __restrict__ a_s,
                                                 const float* __restrict__ a_d,
                                                 float* __restrict__ als,
                                                 float* __restrict__ ald,
                                                 unsigned char* __restrict__ h8) {
    int wave = (blockIdx.x * blockDim.x + threadIdx.x) >> 6;
    int lane = threadIdx.x & 63;
    if (wave >= N_NODES) return;
    ushort4 hu = *(const ushort4*)(h + (long)wave * 256 + lane * 4);
    float hx = bf2f(hu.x), hy = bf2f(hu.y), hz = bf2f(hu.z), hw = bf2f(hu.w);
    // fp8 copy (coalesced 4 B/lane)
    *(unsigned int*)(h8 + (long)wave * 256 + lane * 4) = pack4fp8(hx, hy, hz, hw);
    int head = lane >> 4;
    int cbase = (lane * 4) & 63;
    float4 sv = *(const float4*)(a_s + head * 64 + cbase);
    float4 dv = *(const float4*)(a_d + head * 64 + cbase);
    float ps = hx * sv.x + hy * sv.y + hz * sv.z + hw * sv.w;
    float pd = hx * dv.x + hy * dv.y + hz * dv.z + hw * dv.w;
    #pragma unroll
    for (int off = 1; off < 16; off <<= 1) {
        ps += __shfl_xor(ps, off);
        pd += __shfl_xor(pd, off);
    }
    if ((lane & 15) == 0) {
        als[wave * 4 + head] = ps;
        ald[wave * 4 + head] = pd;
    }
}

__global__ __launch_bounds__(256) void k_logits1(const unsigned short* __restrict__ h,
                                                 const float* __restrict__ a_s,
                                                 const float* __restrict__ a_d,
                                                 float* __restrict__ als,
                                                 float* __restrict__ ald) {
    int wave = (blockIdx.x * blockDim.x + threadIdx.x) >> 6;
    int lane = threadIdx.x & 63;
    if (wave >= N_NODES) return;
    float hv = (lane < OUT_CH) ? bf2f(h[(long)wave * OUT_CH + lane]) : 0.f;
    float ps = (lane < OUT_CH) ? hv * a_s[lane] : 0.f;
    float pd = (lane < OUT_CH) ? hv * a_d[lane] : 0.f;
    #pragma unroll
    for (int off = 1; off < 64; off <<= 1) {
        ps += __shfl_xor(ps, off);
        pd += __shfl_xor(pd, off);
    }
    if (lane == 0) {
        als[wave] = ps;
        ald[wave] = pd;
    }
}

// ---------------------------------------------------------------------------
// Aggregation (4-head), fp8 gather, half-wave edge split. Phase 1: cooperative
// weights into LDS. Phase 2: each half-wave owns one edge, 8 ch/lane via
// dwordx2 (8 B/lane, 256 B/row). Dequant with v_cvt_pk_f32_fp8. fp32
// accumulate, bf16 out = relu(acc/den + bias).
// ---------------------------------------------------------------------------
__global__ __launch_bounds__(256) void k_agg4(const unsigned char* __restrict__ h8,
                                              const int* __restrict__ start,
                                              const int* __restrict__ deg,
                                              const int* __restrict__ eSrc,
                                              const float* __restrict__ als,
                                              const float* __restrict__ ald,
                                              const float* __restrict__ bias,
                                              unsigned short* __restrict__ out) {
    __shared__ float wbuf[4][CAP * 4];
    __shared__ int   sbuf[4][CAP];
    int wid = threadIdx.x >> 6;
    int node = (blockIdx.x * blockDim.x + threadIdx.x) >> 6;
    int lane = threadIdx.x & 63;
    if (node >= N_NODES) return;
    int st = start[node];
    int dgp = (deg[node] + 7) & ~7;
    const int* ep = eSrc + st;

    // ---- phase 1: weights into LDS (16 slots x 4 heads per pass) ----
    int l16 = lane & 15, headw = lane >> 4;
    float aldd4 = ald[node * 4 + headw];
    int ncap = (dgp < CAP) ? dgp : CAP;
    for (int c = 0; c < ncap; c += 16) {
        int slot = c + l16;
        bool ok = (slot < ncap);
        int raw = ok ? ep[slot] : -1;
        int ss = (raw < 0) ? 0 : raw;
        float a = als[(long)ss * 4 + headw] + aldd4;
        float w = (raw < 0) ? 0.f : __expf(lrelu(a));
        if (ok) {
            wbuf[wid][slot * 4 + headw] = w;
            if (headw == 0) sbuf[wid][slot] = ss;
        }
    }

    // ---- phase 2: half-wave per edge, 8 ch/lane (fp8) ----
    int half = lane >> 5;        // which edge of the pair
    int hl = lane & 31;          // half-lane: channels hl*8 .. hl*8+7
    int head8 = hl >> 3;         // head of this lane's channels
    float den = 0.f;
    float acc[8] = {};

    int ncpair = ncap >> 1;      // multiple of 4 (ncap mult of 8)
    int jA = 0, jB = ncpair - 4;

    auto do_pairs = [&](int p0, int p1, int p2, int p3) {
        int slot[4] = {p0 * 2 + half, p1 * 2 + half, p2 * 2 + half, p3 * 2 + half};
        int s[4];
        float w[4];
        #pragma unroll
        for (int u = 0; u < 4; ++u) {
            s[u] = sbuf[wid][slot[u]];
            w[u] = wbuf[wid][slot[u] * 4 + head8];
        }
        uint2 hv[4];
        #pragma unroll
        for (int u = 0; u < 4; ++u)
            hv[u] = *(const uint2*)(h8 + (long)s[u] * 256 + hl * 8);
        #pragma unroll
        for (int u = 0; u < 4; ++u) {
            den += w[u];
            f32x2 p0v = __builtin_amdgcn_cvt_pk_f32_fp8((int)hv[u].x, false);
            f32x2 p1v = __builtin_amdgcn_cvt_pk_f32_fp8((int)hv[u].x, true);
            f32x2 p2v = __builtin_amdgcn_cvt_pk_f32_fp8((int)hv[u].y, false);
            f32x2 p3v = __builtin_amdgcn_cvt_pk_f32_fp8((int)hv[u].y, true);
            acc[0] += w[u] * p0v.x;
            acc[1] += w[u] * p0v.y;
            acc[2] += w[u] * p1v.x;
            acc[3] += w[u] * p1v.y;
            acc[4] += w[u] * p2v.x;
            acc[5] += w[u] * p2v.y;
            acc[6] += w[u] * p3v.x;
            acc[7] += w[u] * p3v.y;
        }
    };

    while (jA < jB) {
        do_pairs(jA, jA + 1, jB, jB + 1);
        do_pairs(jA + 2, jA + 3, jB + 2, jB + 3);
        jA += 4; jB -= 4;
    }
    if (jA == jB) {
        do_pairs(jA, jA + 1, jA + 2, jA + 3);
    }

    // ---- overflow beyond CAP (practically never taken) ----
    if (dgp > ncap) {
        float aldd8 = ald[node * 4 + head8];
        for (int j = ncap; j < dgp; j += 2) {
            int raw = ep[j + half];
            int ss = (raw < 0) ? 0 : raw;
            float w = (raw < 0) ? 0.f : __expf(lrelu(als[(long)ss * 4 + head8] + aldd8));
            uint2 hv = *(const uint2*)(h8 + (long)ss * 256 + hl * 8);
            f32x2 p0v = __builtin_amdgcn_cvt_pk_f32_fp8((int)hv.x, false);
            f32x2 p1v = __builtin_amdgcn_cvt_pk_f32_fp8((int)hv.x, true);
            f32x2 p2v = __builtin_amdgcn_cvt_pk_f32_fp8((int)hv.y, false);
            f32x2 p3v = __builtin_amdgcn_cvt_pk_f32_fp8((int)hv.y, true);
            den += w;
            acc[0] += w * p0v.x;
            acc[1] += w * p0v.y;
            acc[2] += w * p1v.x;
            acc[3] += w * p1v.y;
            acc[4] += w * p2v.x;
            acc[5] += w * p2v.y;
            acc[6] += w * p3v.x;
            acc[7] += w * p3v.y;
        }
    }

    // ---- combine the two halves ----
    den += __shfl_xor(den, 32);
    #pragma unroll
    for (int c = 0; c < 8; ++c) acc[c] += __shfl_xor(acc[c], 32);

    if (half == 0) {
        float inv = 1.f / den;
        int cb = hl * 8;
        float4 b0 = *(const float4*)(bias + cb);
        float4 b1 = *(const float4*)(bias + cb + 4);
        float v0 = fmaxf(acc[0] * inv + b0.x, 0.f);
        float v1 = fmaxf(acc[1] * inv + b0.y, 0.f);
        float v2 = fmaxf(acc[2] * inv + b0.z, 0.f);
        float v3 = fmaxf(acc[3] * inv + b0.w, 0.f);
        float v4 = fmaxf(acc[4] * inv + b1.x, 0.f);
        float v5 = fmaxf(acc[5] * inv + b1.y, 0.f);
        float v6 = fmaxf(acc[6] * inv + b1.z, 0.f);
        float v7 = fmaxf(acc[7] * inv + b1.w, 0.f);
        uint4 o;
        o.x = (unsigned int)f2bf(v0) | ((unsigned int)f2bf(v1) << 16);
        o.y = (unsigned int)f2bf(v2) | ((unsigned int)f2bf(v3) << 16);
        o.z = (unsigned int)f2bf(v4) | ((unsigned int)f2bf(v5) << 16);
        o.w = (unsigned int)f2bf(v6) | ((unsigned int)f2bf(v7) << 16);
        *(uint4*)(out + (long)node * 256 + cb) = o;
    }
}

// ---------------------------------------------------------------------------
// Final layer agg: quad-per-edge, two-ended walk, fused weights + bias +
// log_softmax (bf16 h3 — accuracy-sensitive final layer stays bf16).
// ---------------------------------------------------------------------------
__global__ __launch_bounds__(256) void k_agg1(const unsigned short* __restrict__ h,
                                              const int* __restrict__ start,
                                              const int* __restrict__ deg,
                                              const int* __restrict__ eSrc,
                                              const float* __restrict__ als,
                                              const float* __restrict__ ald,
                                              const float* __restrict__ bias,
                                              float* __restrict__ out) {
    int node = (blockIdx.x * blockDim.x + threadIdx.x) >> 6;
    int lane = threadIdx.x & 63;
    if (node >= N_NODES) return;
    int q = lane >> 4, r = lane & 15;
    bool act = (r < 10);
    int st = start[node];
    int dgp = (deg[node] + 7) & ~7;
    const int* ep = eSrc + st;
    float aldd = ald[node];

    float den = 0.f;
    float4 acc = {0.f, 0.f, 0.f, 0.f};

    int jA = 0, jB = dgp - 4;
    while (jA < jB) {
        int r0 = ep[jA + q], r1 = ep[jB + q];
        int s0 = (r0 < 0) ? 0 : r0;
        int s1 = (r1 < 0) ? 0 : r1;
        float w0 = (r0 < 0) ? 0.f : __expf(lrelu(als[s0] + aldd));
        float w1 = (r1 < 0) ? 0.f : __expf(lrelu(als[s1] + aldd));
        ushort4 h0 = {0, 0, 0, 0}, h1 = {0, 0, 0, 0};
        if (act) {
            h0 = *(const ushort4*)(h + (long)s0 * OUT_CH + r * 4);
            h1 = *(const ushort4*)(h + (long)s1 * OUT_CH + r * 4);
        }
        den += w0 + w1;
        acc.x += w0 * bf2f(h0.x) + w1 * bf2f(h1.x);
        acc.y += w0 * bf2f(h0.y) + w1 * bf2f(h1.y);
        acc.z += w0 * bf2f(h0.z) + w1 * bf2f(h1.z);
        acc.w += w0 * bf2f(h0.w) + w1 * bf2f(h1.w);
        jA += 4; jB -= 4;
    }
    if (jA == jB) {
        int r0 = ep[jA + q];
        int s0 = (r0 < 0) ? 0 : r0;
        float w0 = (r0 < 0) ? 0.f : __expf(lrelu(als[s0] + aldd));
        ushort4 h0 = {0, 0, 0, 0};
        if (act) h0 = *(const ushort4*)(h + (long)s0 * OUT_CH + r * 4);
        den += w0;
        acc.x += w0 * bf2f(h0.x);
        acc.y += w0 * bf2f(h0.y);
        acc.z += w0 * bf2f(h0.z);
        acc.w += w0 * bf2f(h0.w);
    }

    #pragma unroll
    for (int off = 16; off < 64; off <<= 1) {
        acc.x += __shfl_xor(acc.x, off);
        acc.y += __shfl_xor(acc.y, off);
        acc.z += __shfl_xor(acc.z, off);
        acc.w += __shfl_xor(acc.w, off);
        den   += __shfl_xor(den, off);
    }
    float inv = 1.f / den;
    float4 bv = {0.f, 0.f, 0.f, 0.f};
    if (act) bv = *(const float4*)(bias + r * 4);
    float4 v;
    v.x = acc.x * inv + bv.x;
    v.y = acc.y * inv + bv.y;
    v.z = acc.z * inv + bv.z;
    v.w = acc.w * inv + bv.w;
    float mx = act ? fmaxf(fmaxf(v.x, v.y), fmaxf(v.z, v.w)) : -INFINITY;
    #pragma unroll
    for (int off = 1; off < 16; off <<= 1) mx = fmaxf(mx, __shfl_xor(mx, off));
    float sum = act ? (__expf(v.x - mx) + __expf(v.y - mx) + __expf(v.z - mx) + __expf(v.w - mx)) : 0.f;
    #pragma unroll
    for (int off = 1; off < 16; off <<= 1) sum += __shfl_xor(sum, off);
    float lse = mx + logf(sum);
    if (q == 0 && act) {
        float4 o;
        o.x = v.x - lse;
        o.y = v.y - lse;
        o.z = v.z - lse;
        o.w = v.w - lse;
        *(float4*)(out + (long)node * OUT_CH + r * 4) = o;
    }
}

// ---------------------------------------------------------------------------
extern "C" void kernel_launch(void* const* d_in, const int* in_sizes, int n_in,
                              void* d_out, int out_size, void* d_ws, size_t ws_size,
                              hipStream_t stream) {
    (void)in_sizes; (void)n_in; (void)out_size; (void)ws_size;
    const float* x   = (const float*)d_in[0];
    const int*   ei  = (const int*)d_in[1];
    const float* W1  = (const float*)d_in[2];
    const float* as1 = (const float*)d_in[3];
    const float* ad1 = (const float*)d_in[4];
    const float* b1  = (const float*)d_in[5];
    const float* W2  = (const float*)d_in[6];
    const float* as2 = (const float*)d_in[7];
    const float* ad2 = (const float*)d_in[8];
    const float* b2  = (const float*)d_in[9];
    const float* W3  = (const float*)d_in[10];
    const float* as3 = (const float*)d_in[11];
    const float* ad3 = (const float*)d_in[12];
    const float* b3  = (const float*)d_in[13];
    float* out = (float*)d_out;

    char* p = (char*)d_ws;
    auto alloc = [&](size_t b) { char* r = p; p += (b + 255) & ~(size_t)255; return r; };
    int*   deg   = (int*)alloc((size_t)N_NODES * 4);
    int*   start = (int*)alloc((size_t)N_NODES * 4);
    int*   fill  = (int*)alloc((size_t)N_NODES * 4);
    int*   bsum  = (int*)alloc(256 * 4);
    int*   eSrc  = (int*)alloc((size_t)EPAD_MAX * 4);
    float* als   = (float*)alloc((size_t)N_NODES * 4 * 4);
    float* ald   = (float*)alloc((size_t)N_NODES * 4 * 4);
    unsigned short* hAbf = (unsigned short*)alloc((size_t)N_NODES * 256 * 2);
    unsigned short* hBbf = (unsigned short*)alloc((size_t)N_NODES * 256 * 2);
    unsigned short* h3bf = (unsigned short*)alloc((size_t)N_NODES * OUT_CH * 2);
    unsigned char*  hA8  = (unsigned char*)alloc((size_t)N_NODES * 256);
    unsigned short* Wt1  = (unsigned short*)alloc((size_t)256 * IN_CH * 2);
    unsigned short* Wt2  = (unsigned short*)alloc((size_t)256 * 256 * 2);
    unsigned short* Wt3  = (unsigned short*)alloc((size_t)64 * 256 * 2);

    const int NB = (N_NODES + 255) / 256;
    const int EB = (ETOT + 255) / 256;
    const int WB = (N_NODES + 3) / 4;
    const int MB = (N_NODES + 127) / 128;

    // ---- CSR build (padded to multiple of 8 per node) ----
    hipMemsetAsync(deg,  0, (size_t)N_NODES * 4, stream);
    hipMemsetAsync(fill, 0, (size_t)N_NODES * 4, stream);
    hipMemsetAsync(eSrc, 0xFF, (size_t)EPAD_MAX * 4, stream);   // pads -> -1
    k_hist<<<EB, 256, 0, stream>>>(ei, deg);
    k_scan1<<<NB, 256, 0, stream>>>(deg, start, bsum);
    k_scan2<<<1, 256, 0, stream>>>(bsum, NB);
    k_scan3<<<NB, 256, 0, stream>>>(start, bsum);
    k_scatter<<<EB, 256, 0, stream>>>(ei, start, fill, eSrc);

    // ---- weight transposes ----
    k_wt<<<(256 * IN_CH + 255) / 256, 256, 0, stream>>>(W1, Wt1, IN_CH, 256, 256);
    k_wt<<<(256 * 256 + 255) / 256, 256, 0, stream>>>(W2, Wt2, 256, 256, 256);
    k_wt<<<(64 * 256 + 255) / 256, 256, 0, stream>>>(W3, Wt3, 256, OUT_CH, 64);

    // ---- layer 1 (fp32 x staged+converted in-GEMM) ----
    k_mfma<128, 4, 4, true><<<dim3(MB, 2), 256, 0, stream>>>(x, Wt1, hAbf, N_NODES, IN_CH, 256);
    k_logits4<<<WB, 256, 0, stream>>>(hAbf, as1, ad1, als, ald, hA8);
    k_agg4<<<WB, 256, 0, stream>>>(hA8, start, deg, eSrc, als, ald, b1, hBbf);

    // ---- layer 2 ----
    k_mfma<128, 4, 4, false><<<dim3(MB, 2), 256, 0, stream>>>(hBbf, Wt2, hAbf, N_NODES, 256, 256);
    k_logits4<<<WB, 256, 0, stream>>>(hAbf, as2, ad2, als, ald, hA8);
    k_agg4<<<WB, 256, 0, stream>>>(hA8, start, deg, eSrc, als, ald, b2, hBbf);

    // ---- layer 3 ----
    k_mfma<64, 2, 4, false><<<dim3(MB, 1), 256, 0, stream>>>(hBbf, Wt3, h3bf, N_NODES, 256, OUT_CH);
    k_logits1<<<WB, 256, 0, stream>>>(h3bf, as3, ad3, als, ald);
    k_agg1<<<WB, 256, 0, stream>>>(h3bf, start, deg, eSrc, als, ald, b3, out);
}

// Round 11
// 407.208 us; speedup vs baseline: 1.1170x; 1.0092x over previous
//
#include <hip/hip_runtime.h>
#include <math.h>

#define N_NODES 50000
#define N_EDGES 800000
#define ETOT    (N_EDGES + N_NODES)
#define EPAD_MAX 1200000   // >= sum of per-node degrees rounded up to mult of 8
#define IN_CH   128
#define OUT_CH  40
#define NEG     0.2f
#define CAP     128        // max cached slots per node

typedef __attribute__((ext_vector_type(8))) short bf16x8;
typedef __attribute__((ext_vector_type(4))) float f32x4;
typedef __attribute__((ext_vector_type(2))) float f32x2;

__device__ inline unsigned short f2bf(float f) {
    unsigned int u = __float_as_uint(f);
    return (unsigned short)((u + 0x7FFFu + ((u >> 16) & 1u)) >> 16);
}
__device__ inline float bf2f(unsigned short u) {
    return __uint_as_float((unsigned int)u << 16);
}
__device__ inline float lrelu(float a) { return (a > 0.f) ? a : NEG * a; }

// ---------------------------------------------------------------------------
// CSR build: histogram of dst, exclusive scan over degrees padded to 8, scatter
// ---------------------------------------------------------------------------
__global__ void k_hist(const int* __restrict__ ei, int* __restrict__ deg) {
    int i = blockIdx.x * blockDim.x + threadIdx.x;
    if (i >= ETOT) return;
    int d = (i < N_EDGES) ? ei[N_EDGES + i] : (i - N_EDGES);
    atomicAdd(&deg[d], 1);
}

__global__ void k_scan1(const int* __restrict__ deg, int* __restrict__ start,
                        int* __restrict__ bsum) {
    __shared__ int sh[256];
    int tid = threadIdx.x;
    int i = blockIdx.x * 256 + tid;
    int v = (i < N_NODES) ? ((deg[i] + 7) & ~7) : 0;   // padded degree
    int x = v;
    sh[tid] = x;
    __syncthreads();
    #pragma unroll
    for (int off = 1; off < 256; off <<= 1) {
        int t = (tid >= off) ? sh[tid - off] : 0;
        __syncthreads();
        x += t;
        sh[tid] = x;
        __syncthreads();
    }
    if (i < N_NODES) start[i] = x - v;
    if (tid == 255) bsum[blockIdx.x] = x;
}

__global__ void k_scan2(int* __restrict__ bsum, int nb) {
    __shared__ int sh[256];
    int tid = threadIdx.x;
    int v = (tid < nb) ? bsum[tid] : 0;
    int x = v;
    sh[tid] = x;
    __syncthreads();
    #pragma unroll
    for (int off = 1; off < 256; off <<= 1) {
        int t = (tid >= off) ? sh[tid - off] : 0;
        __syncthreads();
        x += t;
        sh[tid] = x;
        __syncthreads();
    }
    if (tid < nb) bsum[tid] = x - v;
}

__global__ void k_scan3(int* __restrict__ start, const int* __restrict__ bsum) {
    int i = blockIdx.x * 256 + threadIdx.x;
    if (i < N_NODES) start[i] += bsum[blockIdx.x];
}

__global__ void k_scatter(const int* __restrict__ ei, const int* __restrict__ start,
                          int* __restrict__ fill, int* __restrict__ eSrc) {
    int i = blockIdx.x * blockDim.x + threadIdx.x;
    if (i >= ETOT) return;
    int s, d;
    if (i < N_EDGES) { s = ei[i]; d = ei[N_EDGES + i]; }
    else             { s = i - N_EDGES; d = s; }
    int pos = start[d] + atomicAdd(&fill[d], 1);
    eSrc[pos] = s;
}

// ---------------------------------------------------------------------------
// Fused weight transpose casts: W[K][N] fp32 -> Wt[Npad][K] bf16, all 3 layers
// ---------------------------------------------------------------------------
__global__ void k_wt_all(const float* __restrict__ W1, const float* __restrict__ W2,
                         const float* __restrict__ W3,
                         unsigned short* __restrict__ Wt1,
                         unsigned short* __restrict__ Wt2,
                         unsigned short* __restrict__ Wt3) {
    int i = blockIdx.x * blockDim.x + threadIdx.x;
    if (i < 32768) {                       // W1: 256 x 128
        int n = i >> 7, k = i & 127;
        Wt1[i] = f2bf(W1[(long)k * 256 + n]);
    } else if (i < 98304) {                // W2: 256 x 256
        int j = i - 32768;
        int n = j >> 8, k = j & 255;
        Wt2[j] = f2bf(W2[(long)k * 256 + n]);
    } else if (i < 114688) {               // W3: 64(pad) x 256
        int j = i - 98304;
        int n = j >> 8, k = j & 255;
        Wt3[j] = (n < OUT_CH) ? f2bf(W3[(long)k * OUT_CH + n]) : (unsigned short)0;
    }
}

// ---------------------------------------------------------------------------
// bf16 MFMA GEMM. CVT: A is fp32, converted during LDS staging.
// FP8OUT: C emitted as fp8 e4m3 (h8 layout, Ncol must be 256);
// otherwise C emitted bf16.
// ---------------------------------------------------------------------------
#define PITCH 40
template<int BN, int FM, int FN, bool CVT, bool FP8OUT>
__global__ __launch_bounds__(256) void k_mfma(const void* __restrict__ Araw,
                                              const unsigned short* __restrict__ Bt,
                                              void* __restrict__ Cout,
                                              int M, int K, int Ncol) {
    __shared__ unsigned short As[128 * PITCH];
    __shared__ unsigned short Bs[BN * PITCH];
    const int WCOLS = BN / (FN * 16);
    int tid = threadIdx.x;
    int wave = tid >> 6, lane = tid & 63;
    int quad = lane >> 4, l16 = lane & 15;
    int wr = wave / WCOLS, wc = wave % WCOLS;
    long row0 = (long)blockIdx.x * 128;
    int col0 = blockIdx.y * BN;

    f32x4 acc[FM][FN] = {};

    for (int k0 = 0; k0 < K; k0 += 32) {
        for (int c = tid; c < 512; c += 256) {
            int r = c >> 2, kp = (c & 3) << 3;
            long gr = row0 + r;
            if (CVT) {
                const float* A32 = (const float*)Araw;
                ushort4 lo = {0,0,0,0}, hi = {0,0,0,0};
                if (gr < M) {
                    float4 v0 = *(const float4*)(A32 + gr * K + k0 + kp);
                    float4 v1 = *(const float4*)(A32 + gr * K + k0 + kp + 4);
                    lo.x = f2bf(v0.x); lo.y = f2bf(v0.y); lo.z = f2bf(v0.z); lo.w = f2bf(v0.w);
                    hi.x = f2bf(v1.x); hi.y = f2bf(v1.y); hi.z = f2bf(v1.z); hi.w = f2bf(v1.w);
                }
                *(ushort4*)(As + r * PITCH + kp) = lo;
                *(ushort4*)(As + r * PITCH + kp + 4) = hi;
            } else {
                const unsigned short* A16 = (const unsigned short*)Araw;
                uint4 v = {0u, 0u, 0u, 0u};
                if (gr < M) v = *(const uint4*)(A16 + gr * K + k0 + kp);
                *(uint4*)(As + r * PITCH + kp) = v;
            }
        }
        for (int c = tid; c < BN * 4; c += 256) {
            int r = c >> 2, kp = (c & 3) << 3;
            uint4 v = *(const uint4*)(Bt + (long)(col0 + r) * K + k0 + kp);
            *(uint4*)(Bs + r * PITCH + kp) = v;
        }
        __syncthreads();
        bf16x8 af[FM], bfr[FN];
        #pragma unroll
        for (int i = 0; i < FM; ++i)
            af[i] = *(const bf16x8*)(As + (wr * FM * 16 + i * 16 + l16) * PITCH + quad * 8);
        #pragma unroll
        for (int j = 0; j < FN; ++j)
            bfr[j] = *(const bf16x8*)(Bs + (wc * FN * 16 + j * 16 + l16) * PITCH + quad * 8);
        #pragma unroll
        for (int i = 0; i < FM; ++i)
            #pragma unroll
            for (int j = 0; j < FN; ++j)
                acc[i][j] = __builtin_amdgcn_mfma_f32_16x16x32_bf16(af[i], bfr[j], acc[i][j], 0, 0, 0);
        __syncthreads();
    }

    if (FP8OUT) {
        // h8[row][col], col = col0 + wc*64 + j*16 + l16 : bytes at stride 16
        unsigned char* C8 = (unsigned char*)Cout;
        #pragma unroll
        for (int i = 0; i < FM; ++i) {
            #pragma unroll
            for (int v = 0; v < 4; ++v) {
                long row = row0 + wr * FM * 16 + i * 16 + quad * 4 + v;
                if (row < M) {
                    int p01 = __builtin_amdgcn_cvt_pk_fp8_f32(acc[i][0][v], acc[i][1][v], 0, false);
                    int p23 = __builtin_amdgcn_cvt_pk_fp8_f32(acc[i][2][v], acc[i][3][v], 0, false);
                    unsigned char* b = C8 + row * 256 + col0 + wc * (FN * 16) + l16;
                    b[0]  = (unsigned char)(p01 & 0xFF);
                    b[16] = (unsigned char)((p01 >> 8) & 0xFF);
                    b[32] = (unsigned char)(p23 & 0xFF);
                    b[48] = (unsigned char)((p23 >> 8) & 0xFF);
                }
            }
        }
    } else {
        unsigned short* C = (unsigned short*)Cout;
        #pragma unroll
        for (int i = 0; i < FM; ++i) {
            long rowb = row0 + wr * FM * 16 + i * 16 + quad * 4;
            #pragma unroll
            for (int j = 0; j < FN; ++j) {
                int col = col0 + wc * FN * 16 + j * 16 + l16;
                if (col < Ncol) {
                    #pragma unroll
                    for (int v = 0; v < 4; ++v) {
                        long r = rowb + v;
                        if (r < M) C[r * Ncol + col] = f2bf(acc[i][j][v]);
                    }
                }
            }
        }
    }
}

// ---------------------------------------------------------------------------
// Attention logits (4-head), reading fp8 h8
// ---------------------------------------------------------------------------
__global__ __launch_bounds__(256) void k_logits4(const unsigned char* __restrict__ h8,
                                                 const float* __restrict__ a_s,
                                                 const float* __restrict__ a_d,
                                                 float* __restrict__ als,
                                                 float* __restrict__ ald) {
    int wave = (blockIdx.x * blockDim.x + threadIdx.x) >> 6;
    int lane = threadIdx.x & 63;
    if (wave >= N_NODES) return;
    unsigned int hu = *(const unsigned int*)(h8 + (long)wave * 256 + lane * 4);
    f32x2 lo = __builtin_amdgcn_cvt_pk_f32_fp8((int)hu, false);
    f32x2 hi = __builtin_amdgcn_cvt_pk_f32_fp8((int)hu, true);
    int head = lane >> 4;
    int cbase = (lane * 4) & 63;
    float4 sv = *(const float4*)(a_s + head * 64 + cbase);
    float4 dv = *(const float4*)(a_d + head * 64 + cbase);
    float ps = lo.x * sv.x + lo.y * sv.y + hi.x * sv.z + hi.y * sv.w;
    float pd = lo.x * dv.x + lo.y * dv.y + hi.x * dv.z + hi.y * dv.w;
    #pragma unroll
    for (int off = 1; off < 16; off <<= 1) {
        ps += __shfl_xor(ps, off);
        pd += __shfl_xor(pd, off);
    }
    if ((lane & 15) == 0) {
        als[wave * 4 + head] = ps;
        ald[wave * 4 + head] = pd;
    }
}

__global__ __launch_bounds__(256) void k_logits1(const unsigned short* __restrict__ h,
                                                 const float* __restrict__ a_s,
                                                 const float* __restrict__ a_d,
                                                 float* __restrict__ als,
                                                 float* __restrict__ ald) {
    int wave = (blockIdx.x * blockDim.x + threadIdx.x) >> 6;
    int lane = threadIdx.x & 63;
    if (wave >= N_NODES) return;
    float hv = (lane < OUT_CH) ? bf2f(h[(long)wave * OUT_CH + lane]) : 0.f;
    float ps = (lane < OUT_CH) ? hv * a_s[lane] : 0.f;
    float pd = (lane < OUT_CH) ? hv * a_d[lane] : 0.f;
    #pragma unroll
    for (int off = 1; off < 64; off <<= 1) {
        ps += __shfl_xor(ps, off);
        pd += __shfl_xor(pd, off);
    }
    if (lane == 0) {
        als[wave] = ps;
        ald[wave] = pd;
    }
}

// ---------------------------------------------------------------------------
// Aggregation (4-head), fp8 gather, half-wave edge split (unchanged from R10).
// ---------------------------------------------------------------------------
__global__ __launch_bounds__(256) void k_agg4(const unsigned char* __restrict__ h8,
                                              const int* __restrict__ start,
                                              const int* __restrict__ deg,
                                              const int* __restrict__ eSrc,
                                              const float* __restrict__ als,
                                              const float* __restrict__ ald,
                                              const float* __restrict__ bias,
                                              unsigned short* __restrict__ out) {
    __shared__ float wbuf[4][CAP * 4];
    __shared__ int   sbuf[4][CAP];
    int wid = threadIdx.x >> 6;
    int node = (blockIdx.x * blockDim.x + threadIdx.x) >> 6;
    int lane = threadIdx.x & 63;
    if (node >= N_NODES) return;
    int st = start[node];
    int dgp = (deg[node] + 7) & ~7;
    const int* ep = eSrc + st;

    // ---- phase 1: weights into LDS (16 slots x 4 heads per pass) ----
    int l16 = lane & 15, headw = lane >> 4;
    float aldd4 = ald[node * 4 + headw];
    int ncap = (dgp < CAP) ? dgp : CAP;
    for (int c = 0; c < ncap; c += 16) {
        int slot = c + l16;
        bool ok = (slot < ncap);
        int raw = ok ? ep[slot] : -1;
        int ss = (raw < 0) ? 0 : raw;
        float a = als[(long)ss * 4 + headw] + aldd4;
        float w = (raw < 0) ? 0.f : __expf(lrelu(a));
        if (ok) {
            wbuf[wid][slot * 4 + headw] = w;
            if (headw == 0) sbuf[wid][slot] = ss;
        }
    }

    // ---- phase 2: half-wave per edge, 8 ch/lane (fp8) ----
    int half = lane >> 5;
    int hl = lane & 31;
    int head8 = hl >> 3;
    float den = 0.f;
    float acc[8] = {};

    int ncpair = ncap >> 1;
    int jA = 0, jB = ncpair - 4;

    auto do_pairs = [&](int p0, int p1, int p2, int p3) {
        int slot[4] = {p0 * 2 + half, p1 * 2 + half, p2 * 2 + half, p3 * 2 + half};
        int s[4];
        float w[4];
        #pragma unroll
        for (int u = 0; u < 4; ++u) {
            s[u] = sbuf[wid][slot[u]];
            w[u] = wbuf[wid][slot[u] * 4 + head8];
        }
        uint2 hv[4];
        #pragma unroll
        for (int u = 0; u < 4; ++u)
            hv[u] = *(const uint2*)(h8 + (long)s[u] * 256 + hl * 8);
        #pragma unroll
        for (int u = 0; u < 4; ++u) {
            den += w[u];
            f32x2 p0v = __builtin_amdgcn_cvt_pk_f32_fp8((int)hv[u].x, false);
            f32x2 p1v = __builtin_amdgcn_cvt_pk_f32_fp8((int)hv[u].x, true);
            f32x2 p2v = __builtin_amdgcn_cvt_pk_f32_fp8((int)hv[u].y, false);
            f32x2 p3v = __builtin_amdgcn_cvt_pk_f32_fp8((int)hv[u].y, true);
            acc[0] += w[u] * p0v.x;
            acc[1] += w[u] * p0v.y;
            acc[2] += w[u] * p1v.x;
            acc[3] += w[u] * p1v.y;
            acc[4] += w[u] * p2v.x;
            acc[5] += w[u] * p2v.y;
            acc[6] += w[u] * p3v.x;
            acc[7] += w[u] * p3v.y;
        }
    };

    while (jA < jB) {
        do_pairs(jA, jA + 1, jB, jB + 1);
        do_pairs(jA + 2, jA + 3, jB + 2, jB + 3);
        jA += 4; jB -= 4;
    }
    if (jA == jB) {
        do_pairs(jA, jA + 1, jA + 2, jA + 3);
    }

    if (dgp > ncap) {
        float aldd8 = ald[node * 4 + head8];
        for (int j = ncap; j < dgp; j += 2) {
            int raw = ep[j + half];
            int ss = (raw < 0) ? 0 : raw;
            float w = (raw < 0) ? 0.f : __expf(lrelu(als[(long)ss * 4 + head8] + aldd8));
            uint2 hv = *(const uint2*)(h8 + (long)ss * 256 + hl * 8);
            f32x2 p0v = __builtin_amdgcn_cvt_pk_f32_fp8((int)hv.x, false);
            f32x2 p1v = __builtin_amdgcn_cvt_pk_f32_fp8((int)hv.x, true);
            f32x2 p2v = __builtin_amdgcn_cvt_pk_f32_fp8((int)hv.y, false);
            f32x2 p3v = __builtin_amdgcn_cvt_pk_f32_fp8((int)hv.y, true);
            den += w;
            acc[0] += w * p0v.x;
            acc[1] += w * p0v.y;
            acc[2] += w * p1v.x;
            acc[3] += w * p1v.y;
            acc[4] += w * p2v.x;
            acc[5] += w * p2v.y;
            acc[6] += w * p3v.x;
            acc[7] += w * p3v.y;
        }
    }

    den += __shfl_xor(den, 32);
    #pragma unroll
    for (int c = 0; c < 8; ++c) acc[c] += __shfl_xor(acc[c], 32);

    if (half == 0) {
        float inv = 1.f / den;
        int cb = hl * 8;
        float4 b0 = *(const float4*)(bias + cb);
        float4 b1 = *(const float4*)(bias + cb + 4);
        float v0 = fmaxf(acc[0] * inv + b0.x, 0.f);
        float v1 = fmaxf(acc[1] * inv + b0.y, 0.f);
        float v2 = fmaxf(acc[2] * inv + b0.z, 0.f);
        float v3 = fmaxf(acc[3] * inv + b0.w, 0.f);
        float v4 = fmaxf(acc[4] * inv + b1.x, 0.f);
        float v5 = fmaxf(acc[5] * inv + b1.y, 0.f);
        float v6 = fmaxf(acc[6] * inv + b1.z, 0.f);
        float v7 = fmaxf(acc[7] * inv + b1.w, 0.f);
        uint4 o;
        o.x = (unsigned int)f2bf(v0) | ((unsigned int)f2bf(v1) << 16);
        o.y = (unsigned int)f2bf(v2) | ((unsigned int)f2bf(v3) << 16);
        o.z = (unsigned int)f2bf(v4) | ((unsigned int)f2bf(v5) << 16);
        o.w = (unsigned int)f2bf(v6) | ((unsigned int)f2bf(v7) << 16);
        *(uint4*)(out + (long)node * 256 + cb) = o;
    }
}

// ---------------------------------------------------------------------------
// Final layer agg: quad-per-edge, two-ended walk, fused weights + bias +
// log_softmax (unchanged).
// ---------------------------------------------------------------------------
__global__ __launch_bounds__(256) void k_agg1(const unsigned short* __restrict__ h,
                                              const int* __restrict__ start,
                                              const int* __restrict__ deg,
                                              const int* __restrict__ eSrc,
                                              const float* __restrict__ als,
                                              const float* __restrict__ ald,
                                              const float* __restrict__ bias,
                                              float* __restrict__ out) {
    int node = (blockIdx.x * blockDim.x + threadIdx.x) >> 6;
    int lane = threadIdx.x & 63;
    if (node >= N_NODES) return;
    int q = lane >> 4, r = lane & 15;
    bool act = (r < 10);
    int st = start[node];
    int dgp = (deg[node] + 7) & ~7;
    const int* ep = eSrc + st;
    float aldd = ald[node];

    float den = 0.f;
    float4 acc = {0.f, 0.f, 0.f, 0.f};

    int jA = 0, jB = dgp - 4;
    while (jA < jB) {
        int r0 = ep[jA + q], r1 = ep[jB + q];
        int s0 = (r0 < 0) ? 0 : r0;
        int s1 = (r1 < 0) ? 0 : r1;
        float w0 = (r0 < 0) ? 0.f : __expf(lrelu(als[s0] + aldd));
        float w1 = (r1 < 0) ? 0.f : __expf(lrelu(als[s1] + aldd));
        ushort4 h0 = {0, 0, 0, 0}, h1 = {0, 0, 0, 0};
        if (act) {
            h0 = *(const ushort4*)(h + (long)s0 * OUT_CH + r * 4);
            h1 = *(const ushort4*)(h + (long)s1 * OUT_CH + r * 4);
        }
        den += w0 + w1;
        acc.x += w0 * bf2f(h0.x) + w1 * bf2f(h1.x);
        acc.y += w0 * bf2f(h0.y) + w1 * bf2f(h1.y);
        acc.z += w0 * bf2f(h0.z) + w1 * bf2f(h1.z);
        acc.w += w0 * bf2f(h0.w) + w1 * bf2f(h1.w);
        jA += 4; jB -= 4;
    }
    if (jA == jB) {
        int r0 = ep[jA + q];
        int s0 = (r0 < 0) ? 0 : r0;
        float w0 = (r0 < 0) ? 0.f : __expf(lrelu(als[s0] + aldd));
        ushort4 h0 = {0, 0, 0, 0};
        if (act) h0 = *(const ushort4*)(h + (long)s0 * OUT_CH + r * 4);
        den += w0;
        acc.x += w0 * bf2f(h0.x);
        acc.y += w0 * bf2f(h0.y);
        acc.z += w0 * bf2f(h0.z);
        acc.w += w0 * bf2f(h0.w);
    }

    #pragma unroll
    for (int off = 16; off < 64; off <<= 1) {
        acc.x += __shfl_xor(acc.x, off);
        acc.y += __shfl_xor(acc.y, off);
        acc.z += __shfl_xor(acc.z, off);
        acc.w += __shfl_xor(acc.w, off);
        den   += __shfl_xor(den, off);
    }
    float inv = 1.f / den;
    float4 bv = {0.f, 0.f, 0.f, 0.f};
    if (act) bv = *(const float4*)(bias + r * 4);
    float4 v;
    v.x = acc.x * inv + bv.x;
    v.y = acc.y * inv + bv.y;
    v.z = acc.z * inv + bv.z;
    v.w = acc.w * inv + bv.w;
    float mx = act ? fmaxf(fmaxf(v.x, v.y), fmaxf(v.z, v.w)) : -INFINITY;
    #pragma unroll
    for (int off = 1; off < 16; off <<= 1) mx = fmaxf(mx, __shfl_xor(mx, off));
    float sum = act ? (__expf(v.x - mx) + __expf(v.y - mx) + __expf(v.z - mx) + __expf(v.w - mx)) : 0.f;
    #pragma unroll
    for (int off = 1; off < 16; off <<= 1) sum += __shfl_xor(sum, off);
    float lse = mx + logf(sum);
    if (q == 0 && act) {
        float4 o;
        o.x = v.x - lse;
        o.y = v.y - lse;
        o.z = v.z - lse;
        o.w = v.w - lse;
        *(float4*)(out + (long)node * OUT_CH + r * 4) = o;
    }
}

// ---------------------------------------------------------------------------
extern "C" void kernel_launch(void* const* d_in, const int* in_sizes, int n_in,
                              void* d_out, int out_size, void* d_ws, size_t ws_size,
                              hipStream_t stream) {
    (void)in_sizes; (void)n_in; (void)out_size; (void)ws_size;
    const float* x   = (const float*)d_in[0];
    const int*   ei  = (const int*)d_in[1];
    const float* W1  = (const float*)d_in[2];
    const float* as1 = (const float*)d_in[3];
    const float* ad1 = (const float*)d_in[4];
    const float* b1  = (const float*)d_in[5];
    const float* W2  = (const float*)d_in[6];
    const float* as2 = (const float*)d_in[7];
    const float* ad2 = (const float*)d_in[8];
    const float* b2  = (const float*)d_in[9];
    const float* W3  = (const float*)d_in[10];
    const float* as3 = (const float*)d_in[11];
    const float* ad3 = (const float*)d_in[12];
    const float* b3  = (const float*)d_in[13];
    float* out = (float*)d_out;

    char* p = (char*)d_ws;
    auto alloc = [&](size_t b) { char* r = p; p += (b + 255) & ~(size_t)255; return r; };
    int*   deg   = (int*)alloc((size_t)N_NODES * 4);
    int*   start = (int*)alloc((size_t)N_NODES * 4);
    int*   fill  = (int*)alloc((size_t)N_NODES * 4);
    int*   bsum  = (int*)alloc(256 * 4);
    int*   eSrc  = (int*)alloc((size_t)EPAD_MAX * 4);
    float* als   = (float*)alloc((size_t)N_NODES * 4 * 4);
    float* ald   = (float*)alloc((size_t)N_NODES * 4 * 4);
    unsigned char*  hA8  = (unsigned char*)alloc((size_t)N_NODES * 256);
    unsigned short* hBbf = (unsigned short*)alloc((size_t)N_NODES * 256 * 2);
    unsigned short* h3bf = (unsigned short*)alloc((size_t)N_NODES * OUT_CH * 2);
    unsigned short* Wt1  = (unsigned short*)alloc((size_t)256 * IN_CH * 2);
    unsigned short* Wt2  = (unsigned short*)alloc((size_t)256 * 256 * 2);
    unsigned short* Wt3  = (unsigned short*)alloc((size_t)64 * 256 * 2);

    const int NB = (N_NODES + 255) / 256;
    const int EB = (ETOT + 255) / 256;
    const int WB = (N_NODES + 3) / 4;
    const int MB = (N_NODES + 127) / 128;

    // ---- CSR build (padded to multiple of 8 per node) ----
    hipMemsetAsync(deg,  0, (size_t)N_NODES * 4, stream);
    hipMemsetAsync(fill, 0, (size_t)N_NODES * 4, stream);
    hipMemsetAsync(eSrc, 0xFF, (size_t)EPAD_MAX * 4, stream);   // pads -> -1
    k_hist<<<EB, 256, 0, stream>>>(ei, deg);
    k_scan1<<<NB, 256, 0, stream>>>(deg, start, bsum);
    k_scan2<<<1, 256, 0, stream>>>(bsum, NB);
    k_scan3<<<NB, 256, 0, stream>>>(start, bsum);
    k_scatter<<<EB, 256, 0, stream>>>(ei, start, fill, eSrc);

    // ---- weight transposes (one launch) ----
    k_wt_all<<<448, 256, 0, stream>>>(W1, W2, W3, Wt1, Wt2, Wt3);

    // ---- layer 1 (fp32 x staged+converted in-GEMM, fp8 out) ----
    k_mfma<128, 4, 4, true, true><<<dim3(MB, 2), 256, 0, stream>>>(x, Wt1, hA8, N_NODES, IN_CH, 256);
    k_logits4<<<WB, 256, 0, stream>>>(hA8, as1, ad1, als, ald);
    k_agg4<<<WB, 256, 0, stream>>>(hA8, start, deg, eSrc, als, ald, b1, hBbf);

    // ---- layer 2 (bf16 in, fp8 out) ----
    k_mfma<128, 4, 4, false, true><<<dim3(MB, 2), 256, 0, stream>>>(hBbf, Wt2, hA8, N_NODES, 256, 256);
    k_logits4<<<WB, 256, 0, stream>>>(hA8, as2, ad2, als, ald);
    k_agg4<<<WB, 256, 0, stream>>>(hA8, start, deg, eSrc, als, ald, b2, hBbf);

    // ---- layer 3 (bf16 in, bf16 out) ----
    k_mfma<64, 2, 4, false, false><<<dim3(MB, 1), 256, 0, stream>>>(hBbf, Wt3, h3bf, N_NODES, 256, OUT_CH);
    k_logits1<<<WB, 256, 0, stream>>>(h3bf, as3, ad3, als, ald);
    k_agg1<<<WB, 256, 0, stream>>>(h3bf, start, deg, eSrc, als, ald, b3, out);
}

// Round 12
// 401.793 us; speedup vs baseline: 1.1320x; 1.0135x over previous
//
#include <hip/hip_runtime.h>
#include <math.h>

#define N_NODES 50000
#define N_EDGES 800000
#define ETOT    (N_EDGES + N_NODES)
#define EPAD_MAX 1200000   // >= sum of per-node degrees rounded up to mult of 8
#define IN_CH   128
#define OUT_CH  40
#define NEG     0.2f
#define CAP     64         // max cached slots per node (Poisson(17) max ~48)

typedef __attribute__((ext_vector_type(8))) short bf16x8;
typedef __attribute__((ext_vector_type(4))) float f32x4;
typedef __attribute__((ext_vector_type(2))) float f32x2;

__device__ inline unsigned short f2bf(float f) {
    unsigned int u = __float_as_uint(f);
    return (unsigned short)((u + 0x7FFFu + ((u >> 16) & 1u)) >> 16);
}
__device__ inline float bf2f(unsigned short u) {
    return __uint_as_float((unsigned int)u << 16);
}
__device__ inline float lrelu(float a) { return (a > 0.f) ? a : NEG * a; }

// ---------------------------------------------------------------------------
// CSR build: histogram of dst, exclusive scan over degrees padded to 8, scatter
// ---------------------------------------------------------------------------
__global__ void k_hist(const int* __restrict__ ei, int* __restrict__ deg) {
    int i = blockIdx.x * blockDim.x + threadIdx.x;
    if (i >= ETOT) return;
    int d = (i < N_EDGES) ? ei[N_EDGES + i] : (i - N_EDGES);
    atomicAdd(&deg[d], 1);
}

__global__ void k_scan1(const int* __restrict__ deg, int* __restrict__ start,
                        int* __restrict__ bsum) {
    __shared__ int sh[256];
    int tid = threadIdx.x;
    int i = blockIdx.x * 256 + tid;
    int v = (i < N_NODES) ? ((deg[i] + 7) & ~7) : 0;   // padded degree
    int x = v;
    sh[tid] = x;
    __syncthreads();
    #pragma unroll
    for (int off = 1; off < 256; off <<= 1) {
        int t = (tid >= off) ? sh[tid - off] : 0;
        __syncthreads();
        x += t;
        sh[tid] = x;
        __syncthreads();
    }
    if (i < N_NODES) start[i] = x - v;
    if (tid == 255) bsum[blockIdx.x] = x;
}

__global__ void k_scan2(int* __restrict__ bsum, int nb) {
    __shared__ int sh[256];
    int tid = threadIdx.x;
    int v = (tid < nb) ? bsum[tid] : 0;
    int x = v;
    sh[tid] = x;
    __syncthreads();
    #pragma unroll
    for (int off = 1; off < 256; off <<= 1) {
        int t = (tid >= off) ? sh[tid - off] : 0;
        __syncthreads();
        x += t;
        sh[tid] = x;
        __syncthreads();
    }
    if (tid < nb) bsum[tid] = x - v;
}

// finalize start and seed fill with the same offsets (scatter bumps fill)
__global__ void k_scan3(int* __restrict__ start, const int* __restrict__ bsum,
                        int* __restrict__ fill) {
    int i = blockIdx.x * 256 + threadIdx.x;
    if (i < N_NODES) {
        int s = start[i] + bsum[blockIdx.x];
        start[i] = s;
        fill[i] = s;
    }
}

__global__ void k_scatter(const int* __restrict__ ei, int* __restrict__ fill,
                          int* __restrict__ eSrc) {
    int i = blockIdx.x * blockDim.x + threadIdx.x;
    if (i >= ETOT) return;
    int s, d;
    if (i < N_EDGES) { s = ei[i]; d = ei[N_EDGES + i]; }
    else             { s = i - N_EDGES; d = s; }
    int pos = atomicAdd(&fill[d], 1);
    eSrc[pos] = s;
}

// ---------------------------------------------------------------------------
// Fused weight transpose casts: W[K][N] fp32 -> Wt[Npad][K] bf16, all 3 layers
// ---------------------------------------------------------------------------
__global__ void k_wt_all(const float* __restrict__ W1, const float* __restrict__ W2,
                         const float* __restrict__ W3,
                         unsigned short* __restrict__ Wt1,
                         unsigned short* __restrict__ Wt2,
                         unsigned short* __restrict__ Wt3) {
    int i = blockIdx.x * blockDim.x + threadIdx.x;
    if (i < 32768) {                       // W1: 256 x 128
        int n = i >> 7, k = i & 127;
        Wt1[i] = f2bf(W1[(long)k * 256 + n]);
    } else if (i < 98304) {                // W2: 256 x 256
        int j = i - 32768;
        int n = j >> 8, k = j & 255;
        Wt2[j] = f2bf(W2[(long)k * 256 + n]);
    } else if (i < 114688) {               // W3: 64(pad) x 256
        int j = i - 98304;
        int n = j >> 8, k = j & 255;
        Wt3[j] = (n < OUT_CH) ? f2bf(W3[(long)k * OUT_CH + n]) : (unsigned short)0;
    }
}

// ---------------------------------------------------------------------------
// bf16 MFMA GEMM. CVT: A is fp32, converted during LDS staging.
// FP8OUT: C emitted as fp8 e4m3 (h8 layout, Ncol must be 256);
// otherwise C emitted bf16.
// ---------------------------------------------------------------------------
#define PITCH 40
template<int BN, int FM, int FN, bool CVT, bool FP8OUT>
__global__ __launch_bounds__(256) void k_mfma(const void* __restrict__ Araw,
                                              const unsigned short* __restrict__ Bt,
                                              void* __restrict__ Cout,
                                              int M, int K, int Ncol) {
    __shared__ unsigned short As[128 * PITCH];
    __shared__ unsigned short Bs[BN * PITCH];
    const int WCOLS = BN / (FN * 16);
    int tid = threadIdx.x;
    int wave = tid >> 6, lane = tid & 63;
    int quad = lane >> 4, l16 = lane & 15;
    int wr = wave / WCOLS, wc = wave % WCOLS;
    long row0 = (long)blockIdx.x * 128;
    int col0 = blockIdx.y * BN;

    f32x4 acc[FM][FN] = {};

    for (int k0 = 0; k0 < K; k0 += 32) {
        for (int c = tid; c < 512; c += 256) {
            int r = c >> 2, kp = (c & 3) << 3;
            long gr = row0 + r;
            if (CVT) {
                const float* A32 = (const float*)Araw;
                ushort4 lo = {0,0,0,0}, hi = {0,0,0,0};
                if (gr < M) {
                    float4 v0 = *(const float4*)(A32 + gr * K + k0 + kp);
                    float4 v1 = *(const float4*)(A32 + gr * K + k0 + kp + 4);
                    lo.x = f2bf(v0.x); lo.y = f2bf(v0.y); lo.z = f2bf(v0.z); lo.w = f2bf(v0.w);
                    hi.x = f2bf(v1.x); hi.y = f2bf(v1.y); hi.z = f2bf(v1.z); hi.w = f2bf(v1.w);
                }
                *(ushort4*)(As + r * PITCH + kp) = lo;
                *(ushort4*)(As + r * PITCH + kp + 4) = hi;
            } else {
                const unsigned short* A16 = (const unsigned short*)Araw;
                uint4 v = {0u, 0u, 0u, 0u};
                if (gr < M) v = *(const uint4*)(A16 + gr * K + k0 + kp);
                *(uint4*)(As + r * PITCH + kp) = v;
            }
        }
        for (int c = tid; c < BN * 4; c += 256) {
            int r = c >> 2, kp = (c & 3) << 3;
            uint4 v = *(const uint4*)(Bt + (long)(col0 + r) * K + k0 + kp);
            *(uint4*)(Bs + r * PITCH + kp) = v;
        }
        __syncthreads();
        bf16x8 af[FM], bfr[FN];
        #pragma unroll
        for (int i = 0; i < FM; ++i)
            af[i] = *(const bf16x8*)(As + (wr * FM * 16 + i * 16 + l16) * PITCH + quad * 8);
        #pragma unroll
        for (int j = 0; j < FN; ++j)
            bfr[j] = *(const bf16x8*)(Bs + (wc * FN * 16 + j * 16 + l16) * PITCH + quad * 8);
        #pragma unroll
        for (int i = 0; i < FM; ++i)
            #pragma unroll
            for (int j = 0; j < FN; ++j)
                acc[i][j] = __builtin_amdgcn_mfma_f32_16x16x32_bf16(af[i], bfr[j], acc[i][j], 0, 0, 0);
        __syncthreads();
    }

    if (FP8OUT) {
        unsigned char* C8 = (unsigned char*)Cout;
        #pragma unroll
        for (int i = 0; i < FM; ++i) {
            #pragma unroll
            for (int v = 0; v < 4; ++v) {
                long row = row0 + wr * FM * 16 + i * 16 + quad * 4 + v;
                if (row < M) {
                    int p01 = __builtin_amdgcn_cvt_pk_fp8_f32(acc[i][0][v], acc[i][1][v], 0, false);
                    int p23 = __builtin_amdgcn_cvt_pk_fp8_f32(acc[i][2][v], acc[i][3][v], 0, false);
                    unsigned char* b = C8 + row * 256 + col0 + wc * (FN * 16) + l16;
                    b[0]  = (unsigned char)(p01 & 0xFF);
                    b[16] = (unsigned char)((p01 >> 8) & 0xFF);
                    b[32] = (unsigned char)(p23 & 0xFF);
                    b[48] = (unsigned char)((p23 >> 8) & 0xFF);
                }
            }
        }
    } else {
        unsigned short* C = (unsigned short*)Cout;
        #pragma unroll
        for (int i = 0; i < FM; ++i) {
            long rowb = row0 + wr * FM * 16 + i * 16 + quad * 4;
            #pragma unroll
            for (int j = 0; j < FN; ++j) {
                int col = col0 + wc * FN * 16 + j * 16 + l16;
                if (col < Ncol) {
                    #pragma unroll
                    for (int v = 0; v < 4; ++v) {
                        long r = rowb + v;
                        if (r < M) C[r * Ncol + col] = f2bf(acc[i][j][v]);
                    }
                }
            }
        }
    }
}

// ---------------------------------------------------------------------------
// Attention logits (4-head), reading fp8 h8
// ---------------------------------------------------------------------------
__global__ __launch_bounds__(256) void k_logits4(const unsigned char* __restrict__ h8,
                                                 const float* __restrict__ a_s,
                                                 const float* __restrict__ a_d,
                                                 float* __restrict__ als,
                                                 float* __restrict__ ald) {
    int wave = (blockIdx.x * blockDim.x + threadIdx.x) >> 6;
    int lane = threadIdx.x & 63;
    if (wave >= N_NODES) return;
    unsigned int hu = *(const unsigned int*)(h8 + (long)wave * 256 + lane * 4);
    f32x2 lo = __builtin_amdgcn_cvt_pk_f32_fp8((int)hu, false);
    f32x2 hi = __builtin_amdgcn_cvt_pk_f32_fp8((int)hu, true);
    int head = lane >> 4;
    int cbase = (lane * 4) & 63;
    float4 sv = *(const float4*)(a_s + head * 64 + cbase);
    float4 dv = *(const float4*)(a_d + head * 64 + cbase);
    float ps = lo.x * sv.x + lo.y * sv.y + hi.x * sv.z + hi.y * sv.w;
    float pd = lo.x * dv.x + lo.y * dv.y + hi.x * dv.z + hi.y * dv.w;
    #pragma unroll
    for (int off = 1; off < 16; off <<= 1) {
        ps += __shfl_xor(ps, off);
        pd += __shfl_xor(pd, off);
    }
    if ((lane & 15) == 0) {
        als[wave * 4 + head] = ps;
        ald[wave * 4 + head] = pd;
    }
}

__global__ __launch_bounds__(256) void k_logits1(const unsigned short* __restrict__ h,
                                                 const float* __restrict__ a_s,
                                                 const float* __restrict__ a_d,
                                                 float* __restrict__ als,
                                                 float* __restrict__ ald) {
    int wave = (blockIdx.x * blockDim.x + threadIdx.x) >> 6;
    int lane = threadIdx.x & 63;
    if (wave >= N_NODES) return;
    float hv = (lane < OUT_CH) ? bf2f(h[(long)wave * OUT_CH + lane]) : 0.f;
    float ps = (lane < OUT_CH) ? hv * a_s[lane] : 0.f;
    float pd = (lane < OUT_CH) ? hv * a_d[lane] : 0.f;
    #pragma unroll
    for (int off = 1; off < 64; off <<= 1) {
        ps += __shfl_xor(ps, off);
        pd += __shfl_xor(pd, off);
    }
    if (lane == 0) {
        als[wave] = ps;
        ald[wave] = pd;
    }
}

// ---------------------------------------------------------------------------
// Aggregation (4-head), fp8 gather, half-wave edge split.
// ---------------------------------------------------------------------------
__global__ __launch_bounds__(256) void k_agg4(const unsigned char* __restrict__ h8,
                                              const int* __restrict__ start,
                                              const int* __restrict__ deg,
                                              const int* __restrict__ eSrc,
                                              const float* __restrict__ als,
                                              const float* __restrict__ ald,
                                              const float* __restrict__ bias,
                                              unsigned short* __restrict__ out) {
    __shared__ float wbuf[4][CAP * 4];
    __shared__ int   sbuf[4][CAP];
    int wid = threadIdx.x >> 6;
    int node = (blockIdx.x * blockDim.x + threadIdx.x) >> 6;
    int lane = threadIdx.x & 63;
    if (node >= N_NODES) return;
    int st = start[node];
    int dgp = (deg[node] + 7) & ~7;
    const int* ep = eSrc + st;

    // ---- phase 1: weights into LDS (16 slots x 4 heads per pass) ----
    int l16 = lane & 15, headw = lane >> 4;
    float aldd4 = ald[node * 4 + headw];
    int ncap = (dgp < CAP) ? dgp : CAP;
    for (int c = 0; c < ncap; c += 16) {
        int slot = c + l16;
        bool ok = (slot < ncap);
        int raw = ok ? ep[slot] : -1;
        int ss = (raw < 0) ? 0 : raw;
        float a = als[(long)ss * 4 + headw] + aldd4;
        float w = (raw < 0) ? 0.f : __expf(lrelu(a));
        if (ok) {
            wbuf[wid][slot * 4 + headw] = w;
            if (headw == 0) sbuf[wid][slot] = ss;
        }
    }

    // ---- phase 2: half-wave per edge, 8 ch/lane (fp8) ----
    int half = lane >> 5;
    int hl = lane & 31;
    int head8 = hl >> 3;
    float den = 0.f;
    float acc[8] = {};

    int ncpair = ncap >> 1;
    int jA = 0, jB = ncpair - 4;

    auto do_pairs = [&](int p0, int p1, int p2, int p3) {
        int slot[4] = {p0 * 2 + half, p1 * 2 + half, p2 * 2 + half, p3 * 2 + half};
        int s[4];
        float w[4];
        #pragma unroll
        for (int u = 0; u < 4; ++u) {
            s[u] = sbuf[wid][slot[u]];
            w[u] = wbuf[wid][slot[u] * 4 + head8];
        }
        uint2 hv[4];
        #pragma unroll
        for (int u = 0; u < 4; ++u)
            hv[u] = *(const uint2*)(h8 + (long)s[u] * 256 + hl * 8);
        #pragma unroll
        for (int u = 0; u < 4; ++u) {
            den += w[u];
            f32x2 p0v = __builtin_amdgcn_cvt_pk_f32_fp8((int)hv[u].x, false);
            f32x2 p1v = __builtin_amdgcn_cvt_pk_f32_fp8((int)hv[u].x, true);
            f32x2 p2v = __builtin_amdgcn_cvt_pk_f32_fp8((int)hv[u].y, false);
            f32x2 p3v = __builtin_amdgcn_cvt_pk_f32_fp8((int)hv[u].y, true);
            acc[0] += w[u] * p0v.x;
            acc[1] += w[u] * p0v.y;
            acc[2] += w[u] * p1v.x;
            acc[3] += w[u] * p1v.y;
            acc[4] += w[u] * p2v.x;
            acc[5] += w[u] * p2v.y;
            acc[6] += w[u] * p3v.x;
            acc[7] += w[u] * p3v.y;
        }
    };

    while (jA < jB) {
        do_pairs(jA, jA + 1, jB, jB + 1);
        do_pairs(jA + 2, jA + 3, jB + 2, jB + 3);
        jA += 4; jB -= 4;
    }
    if (jA == jB) {
        do_pairs(jA, jA + 1, jA + 2, jA + 3);
    }

    if (dgp > ncap) {
        float aldd8 = ald[node * 4 + head8];
        for (int j = ncap; j < dgp; j += 2) {
            int raw = ep[j + half];
            int ss = (raw < 0) ? 0 : raw;
            float w = (raw < 0) ? 0.f : __expf(lrelu(als[(long)ss * 4 + head8] + aldd8));
            uint2 hv = *(const uint2*)(h8 + (long)ss * 256 + hl * 8);
            f32x2 p0v = __builtin_amdgcn_cvt_pk_f32_fp8((int)hv.x, false);
            f32x2 p1v = __builtin_amdgcn_cvt_pk_f32_fp8((int)hv.x, true);
            f32x2 p2v = __builtin_amdgcn_cvt_pk_f32_fp8((int)hv.y, false);
            f32x2 p3v = __builtin_amdgcn_cvt_pk_f32_fp8((int)hv.y, true);
            den += w;
            acc[0] += w * p0v.x;
            acc[1] += w * p0v.y;
            acc[2] += w * p1v.x;
            acc[3] += w * p1v.y;
            acc[4] += w * p2v.x;
            acc[5] += w * p2v.y;
            acc[6] += w * p3v.x;
            acc[7] += w * p3v.y;
        }
    }

    den += __shfl_xor(den, 32);
    #pragma unroll
    for (int c = 0; c < 8; ++c) acc[c] += __shfl_xor(acc[c], 32);

    if (half == 0) {
        float inv = 1.f / den;
        int cb = hl * 8;
        float4 b0 = *(const float4*)(bias + cb);
        float4 b1 = *(const float4*)(bias + cb + 4);
        float v0 = fmaxf(acc[0] * inv + b0.x, 0.f);
        float v1 = fmaxf(acc[1] * inv + b0.y, 0.f);
        float v2 = fmaxf(acc[2] * inv + b0.z, 0.f);
        float v3 = fmaxf(acc[3] * inv + b0.w, 0.f);
        float v4 = fmaxf(acc[4] * inv + b1.x, 0.f);
        float v5 = fmaxf(acc[5] * inv + b1.y, 0.f);
        float v6 = fmaxf(acc[6] * inv + b1.z, 0.f);
        float v7 = fmaxf(acc[7] * inv + b1.w, 0.f);
        uint4 o;
        o.x = (unsigned int)f2bf(v0) | ((unsigned int)f2bf(v1) << 16);
        o.y = (unsigned int)f2bf(v2) | ((unsigned int)f2bf(v3) << 16);
        o.z = (unsigned int)f2bf(v4) | ((unsigned int)f2bf(v5) << 16);
        o.w = (unsigned int)f2bf(v6) | ((unsigned int)f2bf(v7) << 16);
        *(uint4*)(out + (long)node * 256 + cb) = o;
    }
}

// ---------------------------------------------------------------------------
// Final layer agg: quad-per-edge, 16-slot unroll (4 edges/quad in flight),
// fused weights + bias + log_softmax.
// ---------------------------------------------------------------------------
__global__ __launch_bounds__(256) void k_agg1(const unsigned short* __restrict__ h,
                                              const int* __restrict__ start,
                                              const int* __restrict__ deg,
                                              const int* __restrict__ eSrc,
                                              const float* __restrict__ als,
                                              const float* __restrict__ ald,
                                              const float* __restrict__ bias,
                                              float* __restrict__ out) {
    int node = (blockIdx.x * blockDim.x + threadIdx.x) >> 6;
    int lane = threadIdx.x & 63;
    if (node >= N_NODES) return;
    int q = lane >> 4, r = lane & 15;
    bool act = (r < 10);
    int st = start[node];
    int dgp = (deg[node] + 7) & ~7;
    const int* ep = eSrc + st;
    float aldd = ald[node];

    float den = 0.f;
    float4 acc = {0.f, 0.f, 0.f, 0.f};

    int j = 0;
    for (; j + 16 <= dgp; j += 16) {
        int base = j + q * 4;
        int s[4];
        float w[4];
        #pragma unroll
        for (int u = 0; u < 4; ++u) s[u] = ep[base + u];
        #pragma unroll
        for (int u = 0; u < 4; ++u) {
            int raw = s[u];
            int ss = (raw < 0) ? 0 : raw;
            w[u] = (raw < 0) ? 0.f : __expf(lrelu(als[ss] + aldd));
            s[u] = ss;
        }
        ushort4 hh[4];
        #pragma unroll
        for (int u = 0; u < 4; ++u) {
            ushort4 t = {0, 0, 0, 0};
            if (act) t = *(const ushort4*)(h + (long)s[u] * OUT_CH + r * 4);
            hh[u] = t;
        }
        #pragma unroll
        for (int u = 0; u < 4; ++u) {
            den += w[u];
            acc.x += w[u] * bf2f(hh[u].x);
            acc.y += w[u] * bf2f(hh[u].y);
            acc.z += w[u] * bf2f(hh[u].z);
            acc.w += w[u] * bf2f(hh[u].w);
        }
    }
    if (j < dgp) {   // 8-slot tail
        int base = j + q * 2;
        int s[2];
        float w[2];
        #pragma unroll
        for (int u = 0; u < 2; ++u) s[u] = ep[base + u];
        #pragma unroll
        for (int u = 0; u < 2; ++u) {
            int raw = s[u];
            int ss = (raw < 0) ? 0 : raw;
            w[u] = (raw < 0) ? 0.f : __expf(lrelu(als[ss] + aldd));
            s[u] = ss;
        }
        ushort4 hh[2];
        #pragma unroll
        for (int u = 0; u < 2; ++u) {
            ushort4 t = {0, 0, 0, 0};
            if (act) t = *(const ushort4*)(h + (long)s[u] * OUT_CH + r * 4);
            hh[u] = t;
        }
        #pragma unroll
        for (int u = 0; u < 2; ++u) {
            den += w[u];
            acc.x += w[u] * bf2f(hh[u].x);
            acc.y += w[u] * bf2f(hh[u].y);
            acc.z += w[u] * bf2f(hh[u].z);
            acc.w += w[u] * bf2f(hh[u].w);
        }
    }

    // combine the 4 quads (edge subsets)
    #pragma unroll
    for (int off = 16; off < 64; off <<= 1) {
        acc.x += __shfl_xor(acc.x, off);
        acc.y += __shfl_xor(acc.y, off);
        acc.z += __shfl_xor(acc.z, off);
        acc.w += __shfl_xor(acc.w, off);
        den   += __shfl_xor(den, off);
    }
    float inv = 1.f / den;
    float4 bv = {0.f, 0.f, 0.f, 0.f};
    if (act) bv = *(const float4*)(bias + r * 4);
    float4 v;
    v.x = acc.x * inv + bv.x;
    v.y = acc.y * inv + bv.y;
    v.z = acc.z * inv + bv.z;
    v.w = acc.w * inv + bv.w;
    float mx = act ? fmaxf(fmaxf(v.x, v.y), fmaxf(v.z, v.w)) : -INFINITY;
    #pragma unroll
    for (int off = 1; off < 16; off <<= 1) mx = fmaxf(mx, __shfl_xor(mx, off));
    float sum = act ? (__expf(v.x - mx) + __expf(v.y - mx) + __expf(v.z - mx) + __expf(v.w - mx)) : 0.f;
    #pragma unroll
    for (int off = 1; off < 16; off <<= 1) sum += __shfl_xor(sum, off);
    float lse = mx + logf(sum);
    if (q == 0 && act) {
        float4 o;
        o.x = v.x - lse;
        o.y = v.y - lse;
        o.z = v.z - lse;
        o.w = v.w - lse;
        *(float4*)(out + (long)node * OUT_CH + r * 4) = o;
    }
}

// ---------------------------------------------------------------------------
extern "C" void kernel_launch(void* const* d_in, const int* in_sizes, int n_in,
                              void* d_out, int out_size, void* d_ws, size_t ws_size,
                              hipStream_t stream) {
    (void)in_sizes; (void)n_in; (void)out_size; (void)ws_size;
    const float* x   = (const float*)d_in[0];
    const int*   ei  = (const int*)d_in[1];
    const float* W1  = (const float*)d_in[2];
    const float* as1 = (const float*)d_in[3];
    const float* ad1 = (const float*)d_in[4];
    const float* b1  = (const float*)d_in[5];
    const float* W2  = (const float*)d_in[6];
    const float* as2 = (const float*)d_in[7];
    const float* ad2 = (const float*)d_in[8];
    const float* b2  = (const float*)d_in[9];
    const float* W3  = (const float*)d_in[10];
    const float* as3 = (const float*)d_in[11];
    const float* ad3 = (const float*)d_in[12];
    const float* b3  = (const float*)d_in[13];
    float* out = (float*)d_out;

    char* p = (char*)d_ws;
    auto alloc = [&](size_t b) { char* r = p; p += (b + 255) & ~(size_t)255; return r; };
    int*   deg   = (int*)alloc((size_t)N_NODES * 4);
    int*   start = (int*)alloc((size_t)N_NODES * 4);
    int*   fill  = (int*)alloc((size_t)N_NODES * 4);
    int*   bsum  = (int*)alloc(256 * 4);
    int*   eSrc  = (int*)alloc((size_t)EPAD_MAX * 4);
    float* als   = (float*)alloc((size_t)N_NODES * 4 * 4);
    float* ald   = (float*)alloc((size_t)N_NODES * 4 * 4);
    unsigned char*  hA8  = (unsigned char*)alloc((size_t)N_NODES * 256);
    unsigned short* hBbf = (unsigned short*)alloc((size_t)N_NODES * 256 * 2);
    unsigned short* h3bf = (unsigned short*)alloc((size_t)N_NODES * OUT_CH * 2);
    unsigned short* Wt1  = (unsigned short*)alloc((size_t)256 * IN_CH * 2);
    unsigned short* Wt2  = (unsigned short*)alloc((size_t)256 * 256 * 2);
    unsigned short* Wt3  = (unsigned short*)alloc((size_t)64 * 256 * 2);

    const int NB = (N_NODES + 255) / 256;
    const int EB = (ETOT + 255) / 256;
    const int WB = (N_NODES + 3) / 4;
    const int MB = (N_NODES + 127) / 128;

    // ---- CSR build (padded to multiple of 8 per node) ----
    hipMemsetAsync(deg,  0, (size_t)N_NODES * 4, stream);
    hipMemsetAsync(eSrc, 0xFF, (size_t)EPAD_MAX * 4, stream);   // pads -> -1
    k_hist<<<EB, 256, 0, stream>>>(ei, deg);
    k_scan1<<<NB, 256, 0, stream>>>(deg, start, bsum);
    k_scan2<<<1, 256, 0, stream>>>(bsum, NB);
    k_scan3<<<NB, 256, 0, stream>>>(start, bsum, fill);
    k_scatter<<<EB, 256, 0, stream>>>(ei, fill, eSrc);

    // ---- weight transposes (one launch) ----
    k_wt_all<<<448, 256, 0, stream>>>(W1, W2, W3, Wt1, Wt2, Wt3);

    // ---- layer 1 (fp32 x staged+converted in-GEMM, fp8 out) ----
    k_mfma<128, 4, 4, true, true><<<dim3(MB, 2), 256, 0, stream>>>(x, Wt1, hA8, N_NODES, IN_CH, 256);
    k_logits4<<<WB, 256, 0, stream>>>(hA8, as1, ad1, als, ald);
    k_agg4<<<WB, 256, 0, stream>>>(hA8, start, deg, eSrc, als, ald, b1, hBbf);

    // ---- layer 2 (bf16 in, fp8 out) ----
    k_mfma<128, 4, 4, false, true><<<dim3(MB, 2), 256, 0, stream>>>(hBbf, Wt2, hA8, N_NODES, 256, 256);
    k_logits4<<<WB, 256, 0, stream>>>(hA8, as2, ad2, als, ald);
    k_agg4<<<WB, 256, 0, stream>>>(hA8, start, deg, eSrc, als, ald, b2, hBbf);

    // ---- layer 3 (bf16 in, bf16 out) ----
    k_mfma<64, 2, 4, false, false><<<dim3(MB, 1), 256, 0, stream>>>(hBbf, Wt3, h3bf, N_NODES, 256, OUT_CH);
    k_logits1<<<WB, 256, 0, stream>>>(h3bf, as3, ad3, als, ald);
    k_agg1<<<WB, 256, 0, stream>>>(h3bf, start, deg, eSrc, als, ald, b3, out);
}

// Round 13
// 351.349 us; speedup vs baseline: 1.2946x; 1.1436x over previous
//
#include <hip/hip_runtime.h>
#include <math.h>

#define N_NODES 50000
#define N_EDGES 800000
#define ETOT    (N_EDGES + N_NODES)
#define EPAD_MAX 1200000   // >= sum of per-node degrees rounded up to mult of 8
#define IN_CH   128
#define OUT_CH  40
#define NEG     0.2f
#define CAP     64         // max cached slots per node (Poisson(17) max ~48)

// bucketed CSR build
#define P1   32            // coarse partitions
#define NPC  1563          // nodes per coarse (32*1563 >= 50000)
#define CCAP 34000         // capacity per coarse (mean 26563)
#define P2   16            // fine per coarse
#define NPF  98            // nodes per fine (16*98 >= 1563)
#define NFINE (P1 * P2)    // 512
#define FCAP 2400          // capacity per fine (mean ~1660)

typedef __attribute__((ext_vector_type(8))) short bf16x8;
typedef __attribute__((ext_vector_type(4))) float f32x4;
typedef __attribute__((ext_vector_type(2))) float f32x2;

__device__ inline unsigned short f2bf(float f) {
    unsigned int u = __float_as_uint(f);
    return (unsigned short)((u + 0x7FFFu + ((u >> 16) & 1u)) >> 16);
}
__device__ inline float bf2f(unsigned short u) {
    return __uint_as_float((unsigned int)u << 16);
}
__device__ inline float lrelu(float a) { return (a > 0.f) ? a : NEG * a; }

// ---------------------------------------------------------------------------
// Bucketed CSR build
// ---------------------------------------------------------------------------
// Pass 1: coarse bucket by dst/NPC. 256 blocks, grid-stride. Packed (d<<16)|s.
__global__ __launch_bounds__(256) void k_b1(const int* __restrict__ ei,
                                            int* __restrict__ ccur,
                                            unsigned int* __restrict__ cbuf) {
    __shared__ int lcnt[P1], lbase[P1], lcur[P1];
    int tid = threadIdx.x;
    if (tid < P1) lcnt[tid] = 0;
    __syncthreads();
    for (int i = blockIdx.x * 256 + tid; i < ETOT; i += 256 * 256) {
        int d = (i < N_EDGES) ? ei[N_EDGES + i] : (i - N_EDGES);
        atomicAdd(&lcnt[d / NPC], 1);
    }
    __syncthreads();
    if (tid < P1) {
        lbase[tid] = atomicAdd(&ccur[tid], lcnt[tid]);
        lcur[tid] = 0;
    }
    __syncthreads();
    for (int i = blockIdx.x * 256 + tid; i < ETOT; i += 256 * 256) {
        int s, d;
        if (i < N_EDGES) { s = ei[i]; d = ei[N_EDGES + i]; }
        else             { s = i - N_EDGES; d = s; }
        int p = d / NPC;
        int off = atomicAdd(&lcur[p], 1);
        cbuf[(long)p * CCAP + lbase[p] + off] = (unsigned int)s | ((unsigned int)d << 16);
    }
}

// Pass 2: refine coarse partition into 16 fine partitions. 8 blocks per coarse.
__global__ __launch_bounds__(256) void k_b2(const int* __restrict__ ccur,
                                            const unsigned int* __restrict__ cbuf,
                                            int* __restrict__ fcur,
                                            unsigned int* __restrict__ fbuf) {
    __shared__ int lcnt[P2], lbase[P2], lcur2[P2];
    int c = blockIdx.x >> 3;
    int sub = blockIdx.x & 7;
    int tid = threadIdx.x;
    int n = ccur[c];
    if (tid < P2) lcnt[tid] = 0;
    __syncthreads();
    int base = c * NPC;
    for (int i = sub * 256 + tid; i < n; i += 8 * 256) {
        int d = (int)(cbuf[(long)c * CCAP + i] >> 16);
        atomicAdd(&lcnt[(d - base) / NPF], 1);
    }
    __syncthreads();
    if (tid < P2) {
        lbase[tid] = atomicAdd(&fcur[c * P2 + tid], lcnt[tid]);
        lcur2[tid] = 0;
    }
    __syncthreads();
    for (int i = sub * 256 + tid; i < n; i += 8 * 256) {
        unsigned int u = cbuf[(long)c * CCAP + i];
        int d = (int)(u >> 16);
        int j = (d - base) / NPF;
        int off = atomicAdd(&lcur2[j], 1);
        fbuf[(long)(c * P2 + j) * FCAP + lbase[j] + off] = u;
    }
}

// Degrees via LDS counting: one block per fine partition (replaces k_hist).
__global__ __launch_bounds__(256) void k_deg(const int* __restrict__ fcur,
                                             const unsigned int* __restrict__ fbuf,
                                             int* __restrict__ deg) {
    __shared__ int cnt[NPF];
    int f = blockIdx.x;
    int tid = threadIdx.x;
    int c = f >> 4, j = f & 15;
    int n0 = c * NPC + j * NPF;
    int nend = min(min(n0 + NPF, (c + 1) * NPC), N_NODES);
    if (tid < NPF) cnt[tid] = 0;
    __syncthreads();
    int n = fcur[f];
    for (int i = tid; i < n; i += 256)
        atomicAdd(&cnt[(int)(fbuf[(long)f * FCAP + i] >> 16) - n0], 1);
    __syncthreads();
    if (tid < NPF && n0 + tid < nend) deg[n0 + tid] = cnt[tid];
}

__global__ void k_scan1(const int* __restrict__ deg, int* __restrict__ start,
                        int* __restrict__ bsum) {
    __shared__ int sh[256];
    int tid = threadIdx.x;
    int i = blockIdx.x * 256 + tid;
    int v = (i < N_NODES) ? ((deg[i] + 7) & ~7) : 0;   // padded degree
    int x = v;
    sh[tid] = x;
    __syncthreads();
    #pragma unroll
    for (int off = 1; off < 256; off <<= 1) {
        int t = (tid >= off) ? sh[tid - off] : 0;
        __syncthreads();
        x += t;
        sh[tid] = x;
        __syncthreads();
    }
    if (i < N_NODES) start[i] = x - v;
    if (tid == 255) bsum[blockIdx.x] = x;
}

__global__ void k_scan2(int* __restrict__ bsum, int nb) {
    __shared__ int sh[256];
    int tid = threadIdx.x;
    int v = (tid < nb) ? bsum[tid] : 0;
    int x = v;
    sh[tid] = x;
    __syncthreads();
    #pragma unroll
    for (int off = 1; off < 256; off <<= 1) {
        int t = (tid >= off) ? sh[tid - off] : 0;
        __syncthreads();
        x += t;
        sh[tid] = x;
        __syncthreads();
    }
    if (tid < nb) bsum[tid] = x - v;
}

__global__ void k_scan3(int* __restrict__ start, const int* __restrict__ bsum) {
    int i = blockIdx.x * 256 + threadIdx.x;
    if (i < N_NODES) start[i] += bsum[blockIdx.x];
}

// Final scatter: one block per fine partition, offsets in LDS, writes local.
__global__ __launch_bounds__(256) void k_scat(const int* __restrict__ fcur,
                                              const unsigned int* __restrict__ fbuf,
                                              const int* __restrict__ start,
                                              int* __restrict__ eSrc) {
    __shared__ int offs[NPF];
    int f = blockIdx.x;
    int tid = threadIdx.x;
    int c = f >> 4, j = f & 15;
    int n0 = c * NPC + j * NPF;
    int nend = min(min(n0 + NPF, (c + 1) * NPC), N_NODES);
    if (tid < NPF && n0 + tid < nend) offs[tid] = start[n0 + tid];
    __syncthreads();
    int n = fcur[f];
    for (int i = tid; i < n; i += 256) {
        unsigned int u = fbuf[(long)f * FCAP + i];
        int d = (int)(u >> 16);
        int pos = atomicAdd(&offs[d - n0], 1);
        eSrc[pos] = (int)(u & 0xFFFFu);
    }
}

// ---------------------------------------------------------------------------
// Fused weight transpose casts: W[K][N] fp32 -> Wt[Npad][K] bf16, all 3 layers
// ---------------------------------------------------------------------------
__global__ void k_wt_all(const float* __restrict__ W1, const float* __restrict__ W2,
                         const float* __restrict__ W3,
                         unsigned short* __restrict__ Wt1,
                         unsigned short* __restrict__ Wt2,
                         unsigned short* __restrict__ Wt3) {
    int i = blockIdx.x * blockDim.x + threadIdx.x;
    if (i < 32768) {                       // W1: 256 x 128
        int n = i >> 7, k = i & 127;
        Wt1[i] = f2bf(W1[(long)k * 256 + n]);
    } else if (i < 98304) {                // W2: 256 x 256
        int j = i - 32768;
        int n = j >> 8, k = j & 255;
        Wt2[j] = f2bf(W2[(long)k * 256 + n]);
    } else if (i < 114688) {               // W3: 64(pad) x 256
        int j = i - 98304;
        int n = j >> 8, k = j & 255;
        Wt3[j] = (n < OUT_CH) ? f2bf(W3[(long)k * OUT_CH + n]) : (unsigned short)0;
    }
}

// ---------------------------------------------------------------------------
// bf16 MFMA GEMM. CVT: A is fp32, converted during LDS staging.
// FP8OUT: C emitted as fp8 e4m3 (h8 layout, Ncol must be 256);
// otherwise C emitted bf16.
// ---------------------------------------------------------------------------
#define PITCH 40
template<int BN, int FM, int FN, bool CVT, bool FP8OUT>
__global__ __launch_bounds__(256) void k_mfma(const void* __restrict__ Araw,
                                              const unsigned short* __restrict__ Bt,
                                              void* __restrict__ Cout,
                                              int M, int K, int Ncol) {
    __shared__ unsigned short As[128 * PITCH];
    __shared__ unsigned short Bs[BN * PITCH];
    const int WCOLS = BN / (FN * 16);
    int tid = threadIdx.x;
    int wave = tid >> 6, lane = tid & 63;
    int quad = lane >> 4, l16 = lane & 15;
    int wr = wave / WCOLS, wc = wave % WCOLS;
    long row0 = (long)blockIdx.x * 128;
    int col0 = blockIdx.y * BN;

    f32x4 acc[FM][FN] = {};

    for (int k0 = 0; k0 < K; k0 += 32) {
        for (int c = tid; c < 512; c += 256) {
            int r = c >> 2, kp = (c & 3) << 3;
            long gr = row0 + r;
            if (CVT) {
                const float* A32 = (const float*)Araw;
                ushort4 lo = {0,0,0,0}, hi = {0,0,0,0};
                if (gr < M) {
                    float4 v0 = *(const float4*)(A32 + gr * K + k0 + kp);
                    float4 v1 = *(const float4*)(A32 + gr * K + k0 + kp + 4);
                    lo.x = f2bf(v0.x); lo.y = f2bf(v0.y); lo.z = f2bf(v0.z); lo.w = f2bf(v0.w);
                    hi.x = f2bf(v1.x); hi.y = f2bf(v1.y); hi.z = f2bf(v1.z); hi.w = f2bf(v1.w);
                }
                *(ushort4*)(As + r * PITCH + kp) = lo;
                *(ushort4*)(As + r * PITCH + kp + 4) = hi;
            } else {
                const unsigned short* A16 = (const unsigned short*)Araw;
                uint4 v = {0u, 0u, 0u, 0u};
                if (gr < M) v = *(const uint4*)(A16 + gr * K + k0 + kp);
                *(uint4*)(As + r * PITCH + kp) = v;
            }
        }
        for (int c = tid; c < BN * 4; c += 256) {
            int r = c >> 2, kp = (c & 3) << 3;
            uint4 v = *(const uint4*)(Bt + (long)(col0 + r) * K + k0 + kp);
            *(uint4*)(Bs + r * PITCH + kp) = v;
        }
        __syncthreads();
        bf16x8 af[FM], bfr[FN];
        #pragma unroll
        for (int i = 0; i < FM; ++i)
            af[i] = *(const bf16x8*)(As + (wr * FM * 16 + i * 16 + l16) * PITCH + quad * 8);
        #pragma unroll
        for (int j = 0; j < FN; ++j)
            bfr[j] = *(const bf16x8*)(Bs + (wc * FN * 16 + j * 16 + l16) * PITCH + quad * 8);
        #pragma unroll
        for (int i = 0; i < FM; ++i)
            #pragma unroll
            for (int j = 0; j < FN; ++j)
                acc[i][j] = __builtin_amdgcn_mfma_f32_16x16x32_bf16(af[i], bfr[j], acc[i][j], 0, 0, 0);
        __syncthreads();
    }

    if (FP8OUT) {
        unsigned char* C8 = (unsigned char*)Cout;
        #pragma unroll
        for (int i = 0; i < FM; ++i) {
            #pragma unroll
            for (int v = 0; v < 4; ++v) {
                long row = row0 + wr * FM * 16 + i * 16 + quad * 4 + v;
                if (row < M) {
                    int p01 = __builtin_amdgcn_cvt_pk_fp8_f32(acc[i][0][v], acc[i][1][v], 0, false);
                    int p23 = __builtin_amdgcn_cvt_pk_fp8_f32(acc[i][2][v], acc[i][3][v], 0, false);
                    unsigned char* b = C8 + row * 256 + col0 + wc * (FN * 16) + l16;
                    b[0]  = (unsigned char)(p01 & 0xFF);
                    b[16] = (unsigned char)((p01 >> 8) & 0xFF);
                    b[32] = (unsigned char)(p23 & 0xFF);
                    b[48] = (unsigned char)((p23 >> 8) & 0xFF);
                }
            }
        }
    } else {
        unsigned short* C = (unsigned short*)Cout;
        #pragma unroll
        for (int i = 0; i < FM; ++i) {
            long rowb = row0 + wr * FM * 16 + i * 16 + quad * 4;
            #pragma unroll
            for (int j = 0; j < FN; ++j) {
                int col = col0 + wc * FN * 16 + j * 16 + l16;
                if (col < Ncol) {
                    #pragma unroll
                    for (int v = 0; v < 4; ++v) {
                        long r = rowb + v;
                        if (r < M) C[r * Ncol + col] = f2bf(acc[i][j][v]);
                    }
                }
            }
        }
    }
}

// ---------------------------------------------------------------------------
// Attention logits (4-head), reading fp8 h8
// ---------------------------------------------------------------------------
__global__ __launch_bounds__(256) void k_logits4(const unsigned char* __restrict__ h8,
                                                 const float* __restrict__ a_s,
                                                 const float* __restrict__ a_d,
                                                 float* __restrict__ als,
                                                 float* __restrict__ ald) {
    int wave = (blockIdx.x * blockDim.x + threadIdx.x) >> 6;
    int lane = threadIdx.x & 63;
    if (wave >= N_NODES) return;
    unsigned int hu = *(const unsigned int*)(h8 + (long)wave * 256 + lane * 4);
    f32x2 lo = __builtin_amdgcn_cvt_pk_f32_fp8((int)hu, false);
    f32x2 hi = __builtin_amdgcn_cvt_pk_f32_fp8((int)hu, true);
    int head = lane >> 4;
    int cbase = (lane * 4) & 63;
    float4 sv = *(const float4*)(a_s + head * 64 + cbase);
    float4 dv = *(const float4*)(a_d + head * 64 + cbase);
    float ps = lo.x * sv.x + lo.y * sv.y + hi.x * sv.z + hi.y * sv.w;
    float pd = lo.x * dv.x + lo.y * dv.y + hi.x * dv.z + hi.y * dv.w;
    #pragma unroll
    for (int off = 1; off < 16; off <<= 1) {
        ps += __shfl_xor(ps, off);
        pd += __shfl_xor(pd, off);
    }
    if ((lane & 15) == 0) {
        als[wave * 4 + head] = ps;
        ald[wave * 4 + head] = pd;
    }
}

__global__ __launch_bounds__(256) void k_logits1(const unsigned short* __restrict__ h,
                                                 const float* __restrict__ a_s,
                                                 const float* __restrict__ a_d,
                                                 float* __restrict__ als,
                                                 float* __restrict__ ald) {
    int wave = (blockIdx.x * blockDim.x + threadIdx.x) >> 6;
    int lane = threadIdx.x & 63;
    if (wave >= N_NODES) return;
    float hv = (lane < OUT_CH) ? bf2f(h[(long)wave * OUT_CH + lane]) : 0.f;
    float ps = (lane < OUT_CH) ? hv * a_s[lane] : 0.f;
    float pd = (lane < OUT_CH) ? hv * a_d[lane] : 0.f;
    #pragma unroll
    for (int off = 1; off < 64; off <<= 1) {
        ps += __shfl_xor(ps, off);
        pd += __shfl_xor(pd, off);
    }
    if (lane == 0) {
        als[wave] = ps;
        ald[wave] = pd;
    }
}

// ---------------------------------------------------------------------------
// Aggregation (4-head), fp8 gather, half-wave edge split.
// ---------------------------------------------------------------------------
__global__ __launch_bounds__(256) void k_agg4(const unsigned char* __restrict__ h8,
                                              const int* __restrict__ start,
                                              const int* __restrict__ deg,
                                              const int* __restrict__ eSrc,
                                              const float* __restrict__ als,
                                              const float* __restrict__ ald,
                                              const float* __restrict__ bias,
                                              unsigned short* __restrict__ out) {
    __shared__ float wbuf[4][CAP * 4];
    __shared__ int   sbuf[4][CAP];
    int wid = threadIdx.x >> 6;
    int node = (blockIdx.x * blockDim.x + threadIdx.x) >> 6;
    int lane = threadIdx.x & 63;
    if (node >= N_NODES) return;
    int st = start[node];
    int dgp = (deg[node] + 7) & ~7;
    const int* ep = eSrc + st;

    // ---- phase 1: weights into LDS (16 slots x 4 heads per pass) ----
    int l16 = lane & 15, headw = lane >> 4;
    float aldd4 = ald[node * 4 + headw];
    int ncap = (dgp < CAP) ? dgp : CAP;
    for (int c = 0; c < ncap; c += 16) {
        int slot = c + l16;
        bool ok = (slot < ncap);
        int raw = ok ? ep[slot] : -1;
        int ss = (raw < 0) ? 0 : raw;
        float a = als[(long)ss * 4 + headw] + aldd4;
        float w = (raw < 0) ? 0.f : __expf(lrelu(a));
        if (ok) {
            wbuf[wid][slot * 4 + headw] = w;
            if (headw == 0) sbuf[wid][slot] = ss;
        }
    }

    // ---- phase 2: half-wave per edge, 8 ch/lane (fp8) ----
    int half = lane >> 5;
    int hl = lane & 31;
    int head8 = hl >> 3;
    float den = 0.f;
    float acc[8] = {};

    int ncpair = ncap >> 1;
    int jA = 0, jB = ncpair - 4;

    auto do_pairs = [&](int p0, int p1, int p2, int p3) {
        int slot[4] = {p0 * 2 + half, p1 * 2 + half, p2 * 2 + half, p3 * 2 + half};
        int s[4];
        float w[4];
        #pragma unroll
        for (int u = 0; u < 4; ++u) {
            s[u] = sbuf[wid][slot[u]];
            w[u] = wbuf[wid][slot[u] * 4 + head8];
        }
        uint2 hv[4];
        #pragma unroll
        for (int u = 0; u < 4; ++u)
            hv[u] = *(const uint2*)(h8 + (long)s[u] * 256 + hl * 8);
        #pragma unroll
        for (int u = 0; u < 4; ++u) {
            den += w[u];
            f32x2 p0v = __builtin_amdgcn_cvt_pk_f32_fp8((int)hv[u].x, false);
            f32x2 p1v = __builtin_amdgcn_cvt_pk_f32_fp8((int)hv[u].x, true);
            f32x2 p2v = __builtin_amdgcn_cvt_pk_f32_fp8((int)hv[u].y, false);
            f32x2 p3v = __builtin_amdgcn_cvt_pk_f32_fp8((int)hv[u].y, true);
            acc[0] += w[u] * p0v.x;
            acc[1] += w[u] * p0v.y;
            acc[2] += w[u] * p1v.x;
            acc[3] += w[u] * p1v.y;
            acc[4] += w[u] * p2v.x;
            acc[5] += w[u] * p2v.y;
            acc[6] += w[u] * p3v.x;
            acc[7] += w[u] * p3v.y;
        }
    };

    while (jA < jB) {
        do_pairs(jA, jA + 1, jB, jB + 1);
        do_pairs(jA + 2, jA + 3, jB + 2, jB + 3);
        jA += 4; jB -= 4;
    }
    if (jA == jB) {
        do_pairs(jA, jA + 1, jA + 2, jA + 3);
    }

    if (dgp > ncap) {
        float aldd8 = ald[node * 4 + head8];
        for (int j = ncap; j < dgp; j += 2) {
            int raw = ep[j + half];
            int ss = (raw < 0) ? 0 : raw;
            float w = (raw < 0) ? 0.f : __expf(lrelu(als[(long)ss * 4 + head8] + aldd8));
            uint2 hv = *(const uint2*)(h8 + (long)ss * 256 + hl * 8);
            f32x2 p0v = __builtin_amdgcn_cvt_pk_f32_fp8((int)hv.x, false);
            f32x2 p1v = __builtin_amdgcn_cvt_pk_f32_fp8((int)hv.x, true);
            f32x2 p2v = __builtin_amdgcn_cvt_pk_f32_fp8((int)hv.y, false);
            f32x2 p3v = __builtin_amdgcn_cvt_pk_f32_fp8((int)hv.y, true);
            den += w;
            acc[0] += w * p0v.x;
            acc[1] += w * p0v.y;
            acc[2] += w * p1v.x;
            acc[3] += w * p1v.y;
            acc[4] += w * p2v.x;
            acc[5] += w * p2v.y;
            acc[6] += w * p3v.x;
            acc[7] += w * p3v.y;
        }
    }

    den += __shfl_xor(den, 32);
    #pragma unroll
    for (int c = 0; c < 8; ++c) acc[c] += __shfl_xor(acc[c], 32);

    if (half == 0) {
        float inv = 1.f / den;
        int cb = hl * 8;
        float4 b0 = *(const float4*)(bias + cb);
        float4 b1 = *(const float4*)(bias + cb + 4);
        float v0 = fmaxf(acc[0] * inv + b0.x, 0.f);
        float v1 = fmaxf(acc[1] * inv + b0.y, 0.f);
        float v2 = fmaxf(acc[2] * inv + b0.z, 0.f);
        float v3 = fmaxf(acc[3] * inv + b0.w, 0.f);
        float v4 = fmaxf(acc[4] * inv + b1.x, 0.f);
        float v5 = fmaxf(acc[5] * inv + b1.y, 0.f);
        float v6 = fmaxf(acc[6] * inv + b1.z, 0.f);
        float v7 = fmaxf(acc[7] * inv + b1.w, 0.f);
        uint4 o;
        o.x = (unsigned int)f2bf(v0) | ((unsigned int)f2bf(v1) << 16);
        o.y = (unsigned int)f2bf(v2) | ((unsigned int)f2bf(v3) << 16);
        o.z = (unsigned int)f2bf(v4) | ((unsigned int)f2bf(v5) << 16);
        o.w = (unsigned int)f2bf(v6) | ((unsigned int)f2bf(v7) << 16);
        *(uint4*)(out + (long)node * 256 + cb) = o;
    }
}

// ---------------------------------------------------------------------------
// Final layer agg: quad-per-edge, 16-slot unroll, fused weights + bias +
// log_softmax (unchanged from R12).
// ---------------------------------------------------------------------------
__global__ __launch_bounds__(256) void k_agg1(const unsigned short* __restrict__ h,
                                              const int* __restrict__ start,
                                              const int* __restrict__ deg,
                                              const int* __restrict__ eSrc,
                                              const float* __restrict__ als,
                                              const float* __restrict__ ald,
                                              const float* __restrict__ bias,
                                              float* __restrict__ out) {
    int node = (blockIdx.x * blockDim.x + threadIdx.x) >> 6;
    int lane = threadIdx.x & 63;
    if (node >= N_NODES) return;
    int q = lane >> 4, r = lane & 15;
    bool act = (r < 10);
    int st = start[node];
    int dgp = (deg[node] + 7) & ~7;
    const int* ep = eSrc + st;
    float aldd = ald[node];

    float den = 0.f;
    float4 acc = {0.f, 0.f, 0.f, 0.f};

    int j = 0;
    for (; j + 16 <= dgp; j += 16) {
        int base = j + q * 4;
        int s[4];
        float w[4];
        #pragma unroll
        for (int u = 0; u < 4; ++u) s[u] = ep[base + u];
        #pragma unroll
        for (int u = 0; u < 4; ++u) {
            int raw = s[u];
            int ss = (raw < 0) ? 0 : raw;
            w[u] = (raw < 0) ? 0.f : __expf(lrelu(als[ss] + aldd));
            s[u] = ss;
        }
        ushort4 hh[4];
        #pragma unroll
        for (int u = 0; u < 4; ++u) {
            ushort4 t = {0, 0, 0, 0};
            if (act) t = *(const ushort4*)(h + (long)s[u] * OUT_CH + r * 4);
            hh[u] = t;
        }
        #pragma unroll
        for (int u = 0; u < 4; ++u) {
            den += w[u];
            acc.x += w[u] * bf2f(hh[u].x);
            acc.y += w[u] * bf2f(hh[u].y);
            acc.z += w[u] * bf2f(hh[u].z);
            acc.w += w[u] * bf2f(hh[u].w);
        }
    }
    if (j < dgp) {   // 8-slot tail
        int base = j + q * 2;
        int s[2];
        float w[2];
        #pragma unroll
        for (int u = 0; u < 2; ++u) s[u] = ep[base + u];
        #pragma unroll
        for (int u = 0; u < 2; ++u) {
            int raw = s[u];
            int ss = (raw < 0) ? 0 : raw;
            w[u] = (raw < 0) ? 0.f : __expf(lrelu(als[ss] + aldd));
            s[u] = ss;
        }
        ushort4 hh[2];
        #pragma unroll
        for (int u = 0; u < 2; ++u) {
            ushort4 t = {0, 0, 0, 0};
            if (act) t = *(const ushort4*)(h + (long)s[u] * OUT_CH + r * 4);
            hh[u] = t;
        }
        #pragma unroll
        for (int u = 0; u < 2; ++u) {
            den += w[u];
            acc.x += w[u] * bf2f(hh[u].x);
            acc.y += w[u] * bf2f(hh[u].y);
            acc.z += w[u] * bf2f(hh[u].z);
            acc.w += w[u] * bf2f(hh[u].w);
        }
    }

    #pragma unroll
    for (int off = 16; off < 64; off <<= 1) {
        acc.x += __shfl_xor(acc.x, off);
        acc.y += __shfl_xor(acc.y, off);
        acc.z += __shfl_xor(acc.z, off);
        acc.w += __shfl_xor(acc.w, off);
        den   += __shfl_xor(den, off);
    }
    float inv = 1.f / den;
    float4 bv = {0.f, 0.f, 0.f, 0.f};
    if (act) bv = *(const float4*)(bias + r * 4);
    float4 v;
    v.x = acc.x * inv + bv.x;
    v.y = acc.y * inv + bv.y;
    v.z = acc.z * inv + bv.z;
    v.w = acc.w * inv + bv.w;
    float mx = act ? fmaxf(fmaxf(v.x, v.y), fmaxf(v.z, v.w)) : -INFINITY;
    #pragma unroll
    for (int off = 1; off < 16; off <<= 1) mx = fmaxf(mx, __shfl_xor(mx, off));
    float sum = act ? (__expf(v.x - mx) + __expf(v.y - mx) + __expf(v.z - mx) + __expf(v.w - mx)) : 0.f;
    #pragma unroll
    for (int off = 1; off < 16; off <<= 1) sum += __shfl_xor(sum, off);
    float lse = mx + logf(sum);
    if (q == 0 && act) {
        float4 o;
        o.x = v.x - lse;
        o.y = v.y - lse;
        o.z = v.z - lse;
        o.w = v.w - lse;
        *(float4*)(out + (long)node * OUT_CH + r * 4) = o;
    }
}

// ---------------------------------------------------------------------------
extern "C" void kernel_launch(void* const* d_in, const int* in_sizes, int n_in,
                              void* d_out, int out_size, void* d_ws, size_t ws_size,
                              hipStream_t stream) {
    (void)in_sizes; (void)n_in; (void)out_size; (void)ws_size;
    const float* x   = (const float*)d_in[0];
    const int*   ei  = (const int*)d_in[1];
    const float* W1  = (const float*)d_in[2];
    const float* as1 = (const float*)d_in[3];
    const float* ad1 = (const float*)d_in[4];
    const float* b1  = (const float*)d_in[5];
    const float* W2  = (const float*)d_in[6];
    const float* as2 = (const float*)d_in[7];
    const float* ad2 = (const float*)d_in[8];
    const float* b2  = (const float*)d_in[9];
    const float* W3  = (const float*)d_in[10];
    const float* as3 = (const float*)d_in[11];
    const float* ad3 = (const float*)d_in[12];
    const float* b3  = (const float*)d_in[13];
    float* out = (float*)d_out;

    char* p = (char*)d_ws;
    auto alloc = [&](size_t b) { char* r = p; p += (b + 255) & ~(size_t)255; return r; };
    int*   deg   = (int*)alloc((size_t)N_NODES * 4);
    int*   start = (int*)alloc((size_t)N_NODES * 4);
    int*   bsum  = (int*)alloc(256 * 4);
    int*   ccur  = (int*)alloc((size_t)P1 * 4);
    int*   fcur  = (int*)alloc((size_t)NFINE * 4);
    unsigned int* cbuf = (unsigned int*)alloc((size_t)P1 * CCAP * 4);
    unsigned int* fbuf = (unsigned int*)alloc((size_t)NFINE * FCAP * 4);
    int*   eSrc  = (int*)alloc((size_t)EPAD_MAX * 4);
    float* als   = (float*)alloc((size_t)N_NODES * 4 * 4);
    float* ald   = (float*)alloc((size_t)N_NODES * 4 * 4);
    unsigned char*  hA8  = (unsigned char*)alloc((size_t)N_NODES * 256);
    unsigned short* hBbf = (unsigned short*)alloc((size_t)N_NODES * 256 * 2);
    unsigned short* h3bf = (unsigned short*)alloc((size_t)N_NODES * OUT_CH * 2);
    unsigned short* Wt1  = (unsigned short*)alloc((size_t)256 * IN_CH * 2);
    unsigned short* Wt2  = (unsigned short*)alloc((size_t)256 * 256 * 2);
    unsigned short* Wt3  = (unsigned short*)alloc((size_t)64 * 256 * 2);

    const int NB = (N_NODES + 255) / 256;
    const int WB = (N_NODES + 3) / 4;
    const int MB = (N_NODES + 127) / 128;

    // ---- bucketed CSR build ----
    hipMemsetAsync(ccur, 0, (size_t)P1 * 4, stream);
    hipMemsetAsync(fcur, 0, (size_t)NFINE * 4, stream);
    hipMemsetAsync(eSrc, 0xFF, (size_t)EPAD_MAX * 4, stream);   // pads -> -1
    k_b1<<<256, 256, 0, stream>>>(ei, ccur, cbuf);
    k_b2<<<256, 256, 0, stream>>>(ccur, cbuf, fcur, fbuf);
    k_deg<<<NFINE, 256, 0, stream>>>(fcur, fbuf, deg);
    k_scan1<<<NB, 256, 0, stream>>>(deg, start, bsum);
    k_scan2<<<1, 256, 0, stream>>>(bsum, NB);
    k_scan3<<<NB, 256, 0, stream>>>(start, bsum);
    k_scat<<<NFINE, 256, 0, stream>>>(fcur, fbuf, start, eSrc);

    // ---- weight transposes (one launch) ----
    k_wt_all<<<448, 256, 0, stream>>>(W1, W2, W3, Wt1, Wt2, Wt3);

    // ---- layer 1 (fp32 x staged+converted in-GEMM, fp8 out) ----
    k_mfma<128, 4, 4, true, true><<<dim3(MB, 2), 256, 0, stream>>>(x, Wt1, hA8, N_NODES, IN_CH, 256);
    k_logits4<<<WB, 256, 0, stream>>>(hA8, as1, ad1, als, ald);
    k_agg4<<<WB, 256, 0, stream>>>(hA8, start, deg, eSrc, als, ald, b1, hBbf);

    // ---- layer 2 (bf16 in, fp8 out) ----
    k_mfma<128, 4, 4, false, true><<<dim3(MB, 2), 256, 0, stream>>>(hBbf, Wt2, hA8, N_NODES, 256, 256);
    k_logits4<<<WB, 256, 0, stream>>>(hA8, as2, ad2, als, ald);
    k_agg4<<<WB, 256, 0, stream>>>(hA8, start, deg, eSrc, als, ald, b2, hBbf);

    // ---- layer 3 (bf16 in, bf16 out) ----
    k_mfma<64, 2, 4, false, false><<<dim3(MB, 1), 256, 0, stream>>>(hBbf, Wt3, h3bf, N_NODES, 256, OUT_CH);
    k_logits1<<<WB, 256, 0, stream>>>(h3bf, as3, ad3, als, ald);
    k_agg1<<<WB, 256, 0, stream>>>(h3bf, start, deg, eSrc, als, ald, b3, out);
}

// Round 14
// 321.044 us; speedup vs baseline: 1.4168x; 1.0944x over previous
//
#include <hip/hip_runtime.h>
#include <math.h>

#define N_NODES 50000
#define N_EDGES 800000
#define ETOT    (N_EDGES + N_NODES)
#define EPAD_MAX 1200000   // >= sum of per-node degrees rounded up to mult of 8
#define IN_CH   128
#define OUT_CH  40
#define NEG     0.2f
#define CAP     64         // max cached slots per node (Poisson(17) max ~48)

// bucketed CSR build
#define P1   32            // coarse partitions
#define NPC  1563          // nodes per coarse (32*1563 >= 50000)
#define CCAP 34000         // capacity per coarse (mean 26563)
#define P2   16            // fine per coarse
#define NPF  98            // nodes per fine (16*98 >= 1563)
#define NFINE (P1 * P2)    // 512
#define FCAP 2400          // capacity per fine (mean ~1660)

typedef __attribute__((ext_vector_type(8))) short bf16x8;
typedef __attribute__((ext_vector_type(4))) float f32x4;
typedef __attribute__((ext_vector_type(2))) float f32x2;

__device__ inline unsigned short f2bf(float f) {
    unsigned int u = __float_as_uint(f);
    return (unsigned short)((u + 0x7FFFu + ((u >> 16) & 1u)) >> 16);
}
__device__ inline float bf2f(unsigned short u) {
    return __uint_as_float((unsigned int)u << 16);
}
__device__ inline float lrelu(float a) { return (a > 0.f) ? a : NEG * a; }

// ---------------------------------------------------------------------------
// Bucketed CSR build
// ---------------------------------------------------------------------------
__global__ __launch_bounds__(256) void k_b1(const int* __restrict__ ei,
                                            int* __restrict__ ccur,
                                            unsigned int* __restrict__ cbuf) {
    __shared__ int lcnt[P1], lbase[P1], lcur[P1];
    int tid = threadIdx.x;
    if (tid < P1) lcnt[tid] = 0;
    __syncthreads();
    for (int i = blockIdx.x * 256 + tid; i < ETOT; i += 256 * 256) {
        int d = (i < N_EDGES) ? ei[N_EDGES + i] : (i - N_EDGES);
        atomicAdd(&lcnt[d / NPC], 1);
    }
    __syncthreads();
    if (tid < P1) {
        lbase[tid] = atomicAdd(&ccur[tid], lcnt[tid]);
        lcur[tid] = 0;
    }
    __syncthreads();
    for (int i = blockIdx.x * 256 + tid; i < ETOT; i += 256 * 256) {
        int s, d;
        if (i < N_EDGES) { s = ei[i]; d = ei[N_EDGES + i]; }
        else             { s = i - N_EDGES; d = s; }
        int p = d / NPC;
        int off = atomicAdd(&lcur[p], 1);
        cbuf[(long)p * CCAP + lbase[p] + off] = (unsigned int)s | ((unsigned int)d << 16);
    }
}

__global__ __launch_bounds__(256) void k_b2(const int* __restrict__ ccur,
                                            const unsigned int* __restrict__ cbuf,
                                            int* __restrict__ fcur,
                                            unsigned int* __restrict__ fbuf) {
    __shared__ int lcnt[P2], lbase[P2], lcur2[P2];
    int c = blockIdx.x >> 3;
    int sub = blockIdx.x & 7;
    int tid = threadIdx.x;
    int n = ccur[c];
    if (tid < P2) lcnt[tid] = 0;
    __syncthreads();
    int base = c * NPC;
    for (int i = sub * 256 + tid; i < n; i += 8 * 256) {
        int d = (int)(cbuf[(long)c * CCAP + i] >> 16);
        atomicAdd(&lcnt[(d - base) / NPF], 1);
    }
    __syncthreads();
    if (tid < P2) {
        lbase[tid] = atomicAdd(&fcur[c * P2 + tid], lcnt[tid]);
        lcur2[tid] = 0;
    }
    __syncthreads();
    for (int i = sub * 256 + tid; i < n; i += 8 * 256) {
        unsigned int u = cbuf[(long)c * CCAP + i];
        int d = (int)(u >> 16);
        int j = (d - base) / NPF;
        int off = atomicAdd(&lcur2[j], 1);
        fbuf[(long)(c * P2 + j) * FCAP + lbase[j] + off] = u;
    }
}

__global__ __launch_bounds__(256) void k_deg(const int* __restrict__ fcur,
                                             const unsigned int* __restrict__ fbuf,
                                             int* __restrict__ deg) {
    __shared__ int cnt[NPF];
    int f = blockIdx.x;
    int tid = threadIdx.x;
    int c = f >> 4, j = f & 15;
    int n0 = c * NPC + j * NPF;
    int nend = min(min(n0 + NPF, (c + 1) * NPC), N_NODES);
    if (tid < NPF) cnt[tid] = 0;
    __syncthreads();
    int n = fcur[f];
    for (int i = tid; i < n; i += 256)
        atomicAdd(&cnt[(int)(fbuf[(long)f * FCAP + i] >> 16) - n0], 1);
    __syncthreads();
    if (tid < NPF && n0 + tid < nend) deg[n0 + tid] = cnt[tid];
}

__global__ void k_scan1(const int* __restrict__ deg, int* __restrict__ start,
                        int* __restrict__ bsum) {
    __shared__ int sh[256];
    int tid = threadIdx.x;
    int i = blockIdx.x * 256 + tid;
    int v = (i < N_NODES) ? ((deg[i] + 7) & ~7) : 0;   // padded degree
    int x = v;
    sh[tid] = x;
    __syncthreads();
    #pragma unroll
    for (int off = 1; off < 256; off <<= 1) {
        int t = (tid >= off) ? sh[tid - off] : 0;
        __syncthreads();
        x += t;
        sh[tid] = x;
        __syncthreads();
    }
    if (i < N_NODES) start[i] = x - v;
    if (tid == 255) bsum[blockIdx.x] = x;
}

// merged scan2+scan3: each block redundantly scans bsum in LDS, then offsets
__global__ void k_scan3(int* __restrict__ start, const int* __restrict__ bsum,
                        int nb) {
    __shared__ int sh[256];
    __shared__ int ex[256];
    int tid = threadIdx.x;
    int v = (tid < nb) ? bsum[tid] : 0;
    int x = v;
    sh[tid] = x;
    __syncthreads();
    #pragma unroll
    for (int off = 1; off < 256; off <<= 1) {
        int t = (tid >= off) ? sh[tid - off] : 0;
        __syncthreads();
        x += t;
        sh[tid] = x;
        __syncthreads();
    }
    ex[tid] = x - v;
    __syncthreads();
    int add = ex[blockIdx.x];
    int i = blockIdx.x * 256 + tid;
    if (i < N_NODES) start[i] += add;
}

// Final scatter + pad fill: one block per fine partition.
__global__ __launch_bounds__(256) void k_scat(const int* __restrict__ fcur,
                                              const unsigned int* __restrict__ fbuf,
                                              const int* __restrict__ start,
                                              int* __restrict__ eSrc) {
    __shared__ int offs[NPF];
    __shared__ int base[NPF];
    int f = blockIdx.x;
    int tid = threadIdx.x;
    int c = f >> 4, j = f & 15;
    int n0 = c * NPC + j * NPF;
    int nend = min(min(n0 + NPF, (c + 1) * NPC), N_NODES);
    int nn = nend - n0;
    if (tid < NPF && tid < nn) {
        int b = start[n0 + tid];
        offs[tid] = b;
        base[tid] = b;
    }
    __syncthreads();
    int n = fcur[f];
    for (int i = tid; i < n; i += 256) {
        unsigned int u = fbuf[(long)f * FCAP + i];
        int d = (int)(u >> 16);
        int pos = atomicAdd(&offs[d - n0], 1);
        eSrc[pos] = (int)(u & 0xFFFFu);
    }
    __syncthreads();
    if (tid < NPF && tid < nn) {
        int endp = offs[tid];
        int dg = endp - base[tid];
        int stop = base[tid] + ((dg + 7) & ~7);
        for (int k2 = endp; k2 < stop; ++k2) eSrc[k2] = -1;
    }
}

// ---------------------------------------------------------------------------
// Fused weight transpose casts
// ---------------------------------------------------------------------------
__global__ void k_wt_all(const float* __restrict__ W1, const float* __restrict__ W2,
                         const float* __restrict__ W3,
                         unsigned short* __restrict__ Wt1,
                         unsigned short* __restrict__ Wt2,
                         unsigned short* __restrict__ Wt3) {
    int i = blockIdx.x * blockDim.x + threadIdx.x;
    if (i < 32768) {                       // W1: 256 x 128
        int n = i >> 7, k = i & 127;
        Wt1[i] = f2bf(W1[(long)k * 256 + n]);
    } else if (i < 98304) {                // W2: 256 x 256
        int j = i - 32768;
        int n = j >> 8, k = j & 255;
        Wt2[j] = f2bf(W2[(long)k * 256 + n]);
    } else if (i < 114688) {               // W3: 64(pad) x 256
        int j = i - 98304;
        int n = j >> 8, k = j & 255;
        Wt3[j] = (n < OUT_CH) ? f2bf(W3[(long)k * OUT_CH + n]) : (unsigned short)0;
    }
}

// ---------------------------------------------------------------------------
// bf16 MFMA GEMM with FUSED attention logits in the epilogue.
// Each wave's C fragment covers one head's 64 cols -> als/ald computed
// in-wave from fp32 accumulators, no atomics.
// CVT: A fp32->bf16 during staging. FP8OUT: C as fp8 (Ncol=256).
// L4: 4-head logits layout; else single head over OUT_CH cols.
// ---------------------------------------------------------------------------
#define PITCH 40
template<int BN, int FM, int FN, bool CVT, bool FP8OUT, bool L4>
__global__ __launch_bounds__(256) void k_mfma(const void* __restrict__ Araw,
                                              const unsigned short* __restrict__ Bt,
                                              void* __restrict__ Cout,
                                              const float* __restrict__ a_s,
                                              const float* __restrict__ a_d,
                                              float* __restrict__ als,
                                              float* __restrict__ ald,
                                              int M, int K, int Ncol) {
    __shared__ unsigned short As[128 * PITCH];
    __shared__ unsigned short Bs[BN * PITCH];
    const int WCOLS = BN / (FN * 16);
    int tid = threadIdx.x;
    int wave = tid >> 6, lane = tid & 63;
    int quad = lane >> 4, l16 = lane & 15;
    int wr = wave / WCOLS, wc = wave % WCOLS;
    long row0 = (long)blockIdx.x * 128;
    int col0 = blockIdx.y * BN;

    f32x4 acc[FM][FN] = {};

    for (int k0 = 0; k0 < K; k0 += 32) {
        for (int c = tid; c < 512; c += 256) {
            int r = c >> 2, kp = (c & 3) << 3;
            long gr = row0 + r;
            if (CVT) {
                const float* A32 = (const float*)Araw;
                ushort4 lo = {0,0,0,0}, hi = {0,0,0,0};
                if (gr < M) {
                    float4 v0 = *(const float4*)(A32 + gr * K + k0 + kp);
                    float4 v1 = *(const float4*)(A32 + gr * K + k0 + kp + 4);
                    lo.x = f2bf(v0.x); lo.y = f2bf(v0.y); lo.z = f2bf(v0.z); lo.w = f2bf(v0.w);
                    hi.x = f2bf(v1.x); hi.y = f2bf(v1.y); hi.z = f2bf(v1.z); hi.w = f2bf(v1.w);
                }
                *(ushort4*)(As + r * PITCH + kp) = lo;
                *(ushort4*)(As + r * PITCH + kp + 4) = hi;
            } else {
                const unsigned short* A16 = (const unsigned short*)Araw;
                uint4 v = {0u, 0u, 0u, 0u};
                if (gr < M) v = *(const uint4*)(A16 + gr * K + k0 + kp);
                *(uint4*)(As + r * PITCH + kp) = v;
            }
        }
        for (int c = tid; c < BN * 4; c += 256) {
            int r = c >> 2, kp = (c & 3) << 3;
            uint4 v = *(const uint4*)(Bt + (long)(col0 + r) * K + k0 + kp);
            *(uint4*)(Bs + r * PITCH + kp) = v;
        }
        __syncthreads();
        bf16x8 af[FM], bfr[FN];
        #pragma unroll
        for (int i = 0; i < FM; ++i)
            af[i] = *(const bf16x8*)(As + (wr * FM * 16 + i * 16 + l16) * PITCH + quad * 8);
        #pragma unroll
        for (int j = 0; j < FN; ++j)
            bfr[j] = *(const bf16x8*)(Bs + (wc * FN * 16 + j * 16 + l16) * PITCH + quad * 8);
        #pragma unroll
        for (int i = 0; i < FM; ++i)
            #pragma unroll
            for (int j = 0; j < FN; ++j)
                acc[i][j] = __builtin_amdgcn_mfma_f32_16x16x32_bf16(af[i], bfr[j], acc[i][j], 0, 0, 0);
        __syncthreads();
    }

    // ---- fused logits: this wave's 64 cols = one head ----
    {
        int head = L4 ? (blockIdx.y * WCOLS + wc) : 0;
        float as_v[FN], ad_v[FN];
        #pragma unroll
        for (int j = 0; j < FN; ++j) {
            int cidx = j * 16 + l16;
            if (L4) {
                as_v[j] = a_s[head * 64 + cidx];
                ad_v[j] = a_d[head * 64 + cidx];
            } else {
                as_v[j] = (cidx < OUT_CH) ? a_s[cidx] : 0.f;
                ad_v[j] = (cidx < OUT_CH) ? a_d[cidx] : 0.f;
            }
        }
        #pragma unroll
        for (int i = 0; i < FM; ++i) {
            #pragma unroll
            for (int v = 0; v < 4; ++v) {
                float ps = acc[i][0][v] * as_v[0] + acc[i][1][v] * as_v[1]
                         + acc[i][2][v] * as_v[2] + acc[i][3][v] * as_v[3];
                float pd = acc[i][0][v] * ad_v[0] + acc[i][1][v] * ad_v[1]
                         + acc[i][2][v] * ad_v[2] + acc[i][3][v] * ad_v[3];
                #pragma unroll
                for (int off = 1; off < 16; off <<= 1) {
                    ps += __shfl_xor(ps, off);
                    pd += __shfl_xor(pd, off);
                }
                if (l16 == 0) {
                    long row = row0 + wr * (FM * 16) + i * 16 + quad * 4 + v;
                    if (row < M) {
                        if (L4) { als[row * 4 + head] = ps; ald[row * 4 + head] = pd; }
                        else    { als[row] = ps; ald[row] = pd; }
                    }
                }
            }
        }
    }

    if (FP8OUT) {
        unsigned char* C8 = (unsigned char*)Cout;
        #pragma unroll
        for (int i = 0; i < FM; ++i) {
            #pragma unroll
            for (int v = 0; v < 4; ++v) {
                long row = row0 + wr * FM * 16 + i * 16 + quad * 4 + v;
                if (row < M) {
                    int p01 = __builtin_amdgcn_cvt_pk_fp8_f32(acc[i][0][v], acc[i][1][v], 0, false);
                    int p23 = __builtin_amdgcn_cvt_pk_fp8_f32(acc[i][2][v], acc[i][3][v], 0, false);
                    unsigned char* b = C8 + row * 256 + col0 + wc * (FN * 16) + l16;
                    b[0]  = (unsigned char)(p01 & 0xFF);
                    b[16] = (unsigned char)((p01 >> 8) & 0xFF);
                    b[32] = (unsigned char)(p23 & 0xFF);
                    b[48] = (unsigned char)((p23 >> 8) & 0xFF);
                }
            }
        }
    } else {
        unsigned short* C = (unsigned short*)Cout;
        #pragma unroll
        for (int i = 0; i < FM; ++i) {
            long rowb = row0 + wr * FM * 16 + i * 16 + quad * 4;
            #pragma unroll
            for (int j = 0; j < FN; ++j) {
                int col = col0 + wc * FN * 16 + j * 16 + l16;
                if (col < Ncol) {
                    #pragma unroll
                    for (int v = 0; v < 4; ++v) {
                        long r = rowb + v;
                        if (r < M) C[r * Ncol + col] = f2bf(acc[i][j][v]);
                    }
                }
            }
        }
    }
}

// ---------------------------------------------------------------------------
// Aggregation (4-head), fp8 gather, half-wave edge split, packed f32x2 FMA.
// ---------------------------------------------------------------------------
__global__ __launch_bounds__(256) void k_agg4(const unsigned char* __restrict__ h8,
                                              const int* __restrict__ start,
                                              const int* __restrict__ deg,
                                              const int* __restrict__ eSrc,
                                              const float* __restrict__ als,
                                              const float* __restrict__ ald,
                                              const float* __restrict__ bias,
                                              unsigned short* __restrict__ out) {
    __shared__ float wbuf[4][CAP * 4];
    __shared__ int   sbuf[4][CAP];
    int wid = threadIdx.x >> 6;
    int node = (blockIdx.x * blockDim.x + threadIdx.x) >> 6;
    int lane = threadIdx.x & 63;
    if (node >= N_NODES) return;
    int st = start[node];
    int dgp = (deg[node] + 7) & ~7;
    const int* ep = eSrc + st;

    // ---- phase 1: weights into LDS ----
    int l16 = lane & 15, headw = lane >> 4;
    float aldd4 = ald[node * 4 + headw];
    int ncap = (dgp < CAP) ? dgp : CAP;
    for (int c = 0; c < ncap; c += 16) {
        int slot = c + l16;
        bool ok = (slot < ncap);
        int raw = ok ? ep[slot] : -1;
        int ss = (raw < 0) ? 0 : raw;
        float a = als[(long)ss * 4 + headw] + aldd4;
        float w = (raw < 0) ? 0.f : __expf(lrelu(a));
        if (ok) {
            wbuf[wid][slot * 4 + headw] = w;
            if (headw == 0) sbuf[wid][slot] = ss;
        }
    }

    // ---- phase 2: half-wave per edge, 8 ch/lane (fp8), packed FMA ----
    int half = lane >> 5;
    int hl = lane & 31;
    int head8 = hl >> 3;
    float den = 0.f;
    f32x2 acc2[4] = {};

    int ncpair = ncap >> 1;
    int jA = 0, jB = ncpair - 4;

    auto do_pairs = [&](int p0, int p1, int p2, int p3) {
        int slot[4] = {p0 * 2 + half, p1 * 2 + half, p2 * 2 + half, p3 * 2 + half};
        int s[4];
        float w[4];
        #pragma unroll
        for (int u = 0; u < 4; ++u) {
            s[u] = sbuf[wid][slot[u]];
            w[u] = wbuf[wid][slot[u] * 4 + head8];
        }
        uint2 hv[4];
        #pragma unroll
        for (int u = 0; u < 4; ++u)
            hv[u] = *(const uint2*)(h8 + (long)s[u] * 256 + hl * 8);
        #pragma unroll
        for (int u = 0; u < 4; ++u) {
            den += w[u];
            f32x2 w2; w2.x = w[u]; w2.y = w[u];
            acc2[0] += w2 * __builtin_amdgcn_cvt_pk_f32_fp8((int)hv[u].x, false);
            acc2[1] += w2 * __builtin_amdgcn_cvt_pk_f32_fp8((int)hv[u].x, true);
            acc2[2] += w2 * __builtin_amdgcn_cvt_pk_f32_fp8((int)hv[u].y, false);
            acc2[3] += w2 * __builtin_amdgcn_cvt_pk_f32_fp8((int)hv[u].y, true);
        }
    };

    while (jA < jB) {
        do_pairs(jA, jA + 1, jB, jB + 1);
        do_pairs(jA + 2, jA + 3, jB + 2, jB + 3);
        jA += 4; jB -= 4;
    }
    if (jA == jB) {
        do_pairs(jA, jA + 1, jA + 2, jA + 3);
    }

    if (dgp > ncap) {
        float aldd8 = ald[node * 4 + head8];
        for (int j = ncap; j < dgp; j += 2) {
            int raw = ep[j + half];
            int ss = (raw < 0) ? 0 : raw;
            float w = (raw < 0) ? 0.f : __expf(lrelu(als[(long)ss * 4 + head8] + aldd8));
            uint2 hv = *(const uint2*)(h8 + (long)ss * 256 + hl * 8);
            den += w;
            f32x2 w2; w2.x = w; w2.y = w;
            acc2[0] += w2 * __builtin_amdgcn_cvt_pk_f32_fp8((int)hv.x, false);
            acc2[1] += w2 * __builtin_amdgcn_cvt_pk_f32_fp8((int)hv.x, true);
            acc2[2] += w2 * __builtin_amdgcn_cvt_pk_f32_fp8((int)hv.y, false);
            acc2[3] += w2 * __builtin_amdgcn_cvt_pk_f32_fp8((int)hv.y, true);
        }
    }

    den += __shfl_xor(den, 32);
    #pragma unroll
    for (int c = 0; c < 4; ++c) {
        acc2[c].x += __shfl_xor(acc2[c].x, 32);
        acc2[c].y += __shfl_xor(acc2[c].y, 32);
    }

    if (half == 0) {
        float inv = 1.f / den;
        int cb = hl * 8;
        float4 b0 = *(const float4*)(bias + cb);
        float4 b1 = *(const float4*)(bias + cb + 4);
        float v0 = fmaxf(acc2[0].x * inv + b0.x, 0.f);
        float v1 = fmaxf(acc2[0].y * inv + b0.y, 0.f);
        float v2 = fmaxf(acc2[1].x * inv + b0.z, 0.f);
        float v3 = fmaxf(acc2[1].y * inv + b0.w, 0.f);
        float v4 = fmaxf(acc2[2].x * inv + b1.x, 0.f);
        float v5 = fmaxf(acc2[2].y * inv + b1.y, 0.f);
        float v6 = fmaxf(acc2[3].x * inv + b1.z, 0.f);
        float v7 = fmaxf(acc2[3].y * inv + b1.w, 0.f);
        uint4 o;
        o.x = (unsigned int)f2bf(v0) | ((unsigned int)f2bf(v1) << 16);
        o.y = (unsigned int)f2bf(v2) | ((unsigned int)f2bf(v3) << 16);
        o.z = (unsigned int)f2bf(v4) | ((unsigned int)f2bf(v5) << 16);
        o.w = (unsigned int)f2bf(v6) | ((unsigned int)f2bf(v7) << 16);
        *(uint4*)(out + (long)node * 256 + cb) = o;
    }
}

// ---------------------------------------------------------------------------
// Final layer agg: quad-per-edge, 16-slot unroll, fused weights + bias +
// log_softmax.
// ---------------------------------------------------------------------------
__global__ __launch_bounds__(256) void k_agg1(const unsigned short* __restrict__ h,
                                              const int* __restrict__ start,
                                              const int* __restrict__ deg,
                                              const int* __restrict__ eSrc,
                                              const float* __restrict__ als,
                                              const float* __restrict__ ald,
                                              const float* __restrict__ bias,
                                              float* __restrict__ out) {
    int node = (blockIdx.x * blockDim.x + threadIdx.x) >> 6;
    int lane = threadIdx.x & 63;
    if (node >= N_NODES) return;
    int q = lane >> 4, r = lane & 15;
    bool act = (r < 10);
    int st = start[node];
    int dgp = (deg[node] + 7) & ~7;
    const int* ep = eSrc + st;
    float aldd = ald[node];

    float den = 0.f;
    float4 acc = {0.f, 0.f, 0.f, 0.f};

    int j = 0;
    for (; j + 16 <= dgp; j += 16) {
        int base = j + q * 4;
        int s[4];
        float w[4];
        #pragma unroll
        for (int u = 0; u < 4; ++u) s[u] = ep[base + u];
        #pragma unroll
        for (int u = 0; u < 4; ++u) {
            int raw = s[u];
            int ss = (raw < 0) ? 0 : raw;
            w[u] = (raw < 0) ? 0.f : __expf(lrelu(als[ss] + aldd));
            s[u] = ss;
        }
        ushort4 hh[4];
        #pragma unroll
        for (int u = 0; u < 4; ++u) {
            ushort4 t = {0, 0, 0, 0};
            if (act) t = *(const ushort4*)(h + (long)s[u] * OUT_CH + r * 4);
            hh[u] = t;
        }
        #pragma unroll
        for (int u = 0; u < 4; ++u) {
            den += w[u];
            acc.x += w[u] * bf2f(hh[u].x);
            acc.y += w[u] * bf2f(hh[u].y);
            acc.z += w[u] * bf2f(hh[u].z);
            acc.w += w[u] * bf2f(hh[u].w);
        }
    }
    if (j < dgp) {   // 8-slot tail
        int base = j + q * 2;
        int s[2];
        float w[2];
        #pragma unroll
        for (int u = 0; u < 2; ++u) s[u] = ep[base + u];
        #pragma unroll
        for (int u = 0; u < 2; ++u) {
            int raw = s[u];
            int ss = (raw < 0) ? 0 : raw;
            w[u] = (raw < 0) ? 0.f : __expf(lrelu(als[ss] + aldd));
            s[u] = ss;
        }
        ushort4 hh[2];
        #pragma unroll
        for (int u = 0; u < 2; ++u) {
            ushort4 t = {0, 0, 0, 0};
            if (act) t = *(const ushort4*)(h + (long)s[u] * OUT_CH + r * 4);
            hh[u] = t;
        }
        #pragma unroll
        for (int u = 0; u < 2; ++u) {
            den += w[u];
            acc.x += w[u] * bf2f(hh[u].x);
            acc.y += w[u] * bf2f(hh[u].y);
            acc.z += w[u] * bf2f(hh[u].z);
            acc.w += w[u] * bf2f(hh[u].w);
        }
    }

    #pragma unroll
    for (int off = 16; off < 64; off <<= 1) {
        acc.x += __shfl_xor(acc.x, off);
        acc.y += __shfl_xor(acc.y, off);
        acc.z += __shfl_xor(acc.z, off);
        acc.w += __shfl_xor(acc.w, off);
        den   += __shfl_xor(den, off);
    }
    float inv = 1.f / den;
    float4 bv = {0.f, 0.f, 0.f, 0.f};
    if (act) bv = *(const float4*)(bias + r * 4);
    float4 v;
    v.x = acc.x * inv + bv.x;
    v.y = acc.y * inv + bv.y;
    v.z = acc.z * inv + bv.z;
    v.w = acc.w * inv + bv.w;
    float mx = act ? fmaxf(fmaxf(v.x, v.y), fmaxf(v.z, v.w)) : -INFINITY;
    #pragma unroll
    for (int off = 1; off < 16; off <<= 1) mx = fmaxf(mx, __shfl_xor(mx, off));
    float sum = act ? (__expf(v.x - mx) + __expf(v.y - mx) + __expf(v.z - mx) + __expf(v.w - mx)) : 0.f;
    #pragma unroll
    for (int off = 1; off < 16; off <<= 1) sum += __shfl_xor(sum, off);
    float lse = mx + logf(sum);
    if (q == 0 && act) {
        float4 o;
        o.x = v.x - lse;
        o.y = v.y - lse;
        o.z = v.z - lse;
        o.w = v.w - lse;
        *(float4*)(out + (long)node * OUT_CH + r * 4) = o;
    }
}

// ---------------------------------------------------------------------------
extern "C" void kernel_launch(void* const* d_in, const int* in_sizes, int n_in,
                              void* d_out, int out_size, void* d_ws, size_t ws_size,
                              hipStream_t stream) {
    (void)in_sizes; (void)n_in; (void)out_size; (void)ws_size;
    const float* x   = (const float*)d_in[0];
    const int*   ei  = (const int*)d_in[1];
    const float* W1  = (const float*)d_in[2];
    const float* as1 = (const float*)d_in[3];
    const float* ad1 = (const float*)d_in[4];
    const float* b1  = (const float*)d_in[5];
    const float* W2  = (const float*)d_in[6];
    const float* as2 = (const float*)d_in[7];
    const float* ad2 = (const float*)d_in[8];
    const float* b2  = (const float*)d_in[9];
    const float* W3  = (const float*)d_in[10];
    const float* as3 = (const float*)d_in[11];
    const float* ad3 = (const float*)d_in[12];
    const float* b3  = (const float*)d_in[13];
    float* out = (float*)d_out;

    char* p = (char*)d_ws;
    auto alloc = [&](size_t b) { char* r = p; p += (b + 255) & ~(size_t)255; return r; };
    int*   deg   = (int*)alloc((size_t)N_NODES * 4);
    int*   start = (int*)alloc((size_t)N_NODES * 4);
    int*   bsum  = (int*)alloc(256 * 4);
    int*   cnts  = (int*)alloc((size_t)(P1 + NFINE) * 4);   // ccur | fcur
    unsigned int* cbuf = (unsigned int*)alloc((size_t)P1 * CCAP * 4);
    unsigned int* fbuf = (unsigned int*)alloc((size_t)NFINE * FCAP * 4);
    int*   eSrc  = (int*)alloc((size_t)EPAD_MAX * 4);
    float* als   = (float*)alloc((size_t)N_NODES * 4 * 4);
    float* ald   = (float*)alloc((size_t)N_NODES * 4 * 4);
    unsigned char*  hA8  = (unsigned char*)alloc((size_t)N_NODES * 256);
    unsigned short* hBbf = (unsigned short*)alloc((size_t)N_NODES * 256 * 2);
    unsigned short* h3bf = (unsigned short*)alloc((size_t)N_NODES * OUT_CH * 2);
    unsigned short* Wt1  = (unsigned short*)alloc((size_t)256 * IN_CH * 2);
    unsigned short* Wt2  = (unsigned short*)alloc((size_t)256 * 256 * 2);
    unsigned short* Wt3  = (unsigned short*)alloc((size_t)64 * 256 * 2);
    int* ccur = cnts;
    int* fcur = cnts + P1;

    const int NB = (N_NODES + 255) / 256;
    const int WB = (N_NODES + 3) / 4;
    const int MB = (N_NODES + 127) / 128;

    // ---- bucketed CSR build ----
    hipMemsetAsync(cnts, 0, (size_t)(P1 + NFINE) * 4, stream);
    k_b1<<<256, 256, 0, stream>>>(ei, ccur, cbuf);
    k_b2<<<256, 256, 0, stream>>>(ccur, cbuf, fcur, fbuf);
    k_deg<<<NFINE, 256, 0, stream>>>(fcur, fbuf, deg);
    k_scan1<<<NB, 256, 0, stream>>>(deg, start, bsum);
    k_scan3<<<NB, 256, 0, stream>>>(start, bsum, NB);
    k_scat<<<NFINE, 256, 0, stream>>>(fcur, fbuf, start, eSrc);

    // ---- weight transposes (one launch) ----
    k_wt_all<<<448, 256, 0, stream>>>(W1, W2, W3, Wt1, Wt2, Wt3);

    // ---- layer 1 (fp32 in, fp8 out, fused logits) ----
    k_mfma<128, 4, 4, true, true, true><<<dim3(MB, 2), 256, 0, stream>>>(
        x, Wt1, hA8, as1, ad1, als, ald, N_NODES, IN_CH, 256);
    k_agg4<<<WB, 256, 0, stream>>>(hA8, start, deg, eSrc, als, ald, b1, hBbf);

    // ---- layer 2 (bf16 in, fp8 out, fused logits) ----
    k_mfma<128, 4, 4, false, true, true><<<dim3(MB, 2), 256, 0, stream>>>(
        hBbf, Wt2, hA8, as2, ad2, als, ald, N_NODES, 256, 256);
    k_agg4<<<WB, 256, 0, stream>>>(hA8, start, deg, eSrc, als, ald, b2, hBbf);

    // ---- layer 3 (bf16 in, bf16 out, fused single-head logits) ----
    k_mfma<64, 2, 4, false, false, false><<<dim3(MB, 1), 256, 0, stream>>>(
        hBbf, Wt3, h3bf, as3, ad3, als, ald, N_NODES, 256, OUT_CH);
    k_agg1<<<WB, 256, 0, stream>>>(h3bf, start, deg, eSrc, als, ald, b3, out);
}